// Round 5
// baseline (1092.935 us; speedup 1.0000x reference)
//
#include <hip/hip_runtime.h>
#include <math.h>

typedef unsigned short u16;
typedef __attribute__((ext_vector_type(8))) short bf16x8;
typedef __attribute__((ext_vector_type(4))) float f32x4;

#define B_N 8
#define LSEQ 2048
#define D_INx 1024
#define D_MODELx 1024
#define D_STATEx 128
#define D_INNERx 2048
#define NHEADSx 32
#define HEADDIMx 64
#define CONV_DIMx 2304
#define D_IN_PROJx 4384
#define CHUNKx 64
#define NCHUNKx 32
#define NTOK (B_N*LSEQ)   // 16384

#define LDX 2336
#define XB_B 2048
#define XB_C 2176
#define XB_DT 2304

// ---------- bf16 helpers (storage only; math fp32) ----------
__device__ __forceinline__ float b2f(u16 u) {
    return __uint_as_float(((unsigned)u) << 16);
}
__device__ __forceinline__ u16 f2b(float f) {
    unsigned u = __float_as_uint(f);
    return (u16)((u + 0x7FFFu + ((u >> 16) & 1u)) >> 16);  // RNE
}

__device__ __forceinline__ float block_sum(float v) {
    __shared__ float sm[8];
    int lane = threadIdx.x & 63, wid = threadIdx.x >> 6;
    #pragma unroll
    for (int o = 32; o; o >>= 1) v += __shfl_xor(v, o);
    __syncthreads();
    if (lane == 0) sm[wid] = v;
    __syncthreads();
    float r = 0.f;
    int nw = blockDim.x >> 6;
    for (int w = 0; w < nw; ++w) r += sm[w];
    return r;
}

__device__ __forceinline__ float silu_f(float x) {
    return x / (1.f + expf(-x));
}

// ---------- fp32 -> bf16 conversion ----------
__global__ __launch_bounds__(256) void cvt_f2b_k(const float* __restrict__ in,
                                                 u16* __restrict__ out, int n4) {
    int i = blockIdx.x * 256 + threadIdx.x;
    if (i >= n4) return;
    float4 v = ((const float4*)in)[i];
    ushort4 o;
    o.x = f2b(v.x); o.y = f2b(v.y); o.z = f2b(v.z); o.w = f2b(v.w);
    ((ushort4*)out)[i] = o;
}

// ---------- bf16 MFMA GEMM (m97 structure, verified round 3) ----------
template<int CBF>
__global__ __launch_bounds__(256) void gemm_mfma(const u16* __restrict__ A,
                                                 const u16* __restrict__ W,
                                                 const float* __restrict__ bias,
                                                 void* __restrict__ Cv,
                                                 int M, int N, int K, int lda, int ldc) {
    __shared__ u16 As[128 * 32];
    __shared__ u16 Bs[128 * 32];

    int nwgx = gridDim.x;
    int nwg = nwgx * gridDim.y;
    int bid = blockIdx.y * nwgx + blockIdx.x;
    int cpx = nwg >> 3;
    bid = (bid & 7) * cpx + (bid >> 3);
    int bm = (bid / nwgx) * 128;
    int bn = (bid % nwgx) * 128;

    int tid = threadIdx.x, wid = tid >> 6, lane = tid & 63;
    int lr = lane & 15, lk = (lane >> 4) << 3;
    int wr = (wid >> 1) << 6, wc = (wid & 1) << 6;

    const u16* srcp[4];
    u16* ldsp[4];
    #pragma unroll
    for (int cc = 0; cc < 4; ++cc) {
        int ch = wid * 4 + cc;
        int r = lane >> 2, col8 = (lane & 3) << 3;
        if (ch < 8) {
            srcp[cc] = A + (size_t)(bm + ch * 16 + r) * lda + col8;
            ldsp[cc] = &As[ch * 512];
        } else {
            srcp[cc] = W + (size_t)(bn + (ch - 8) * 16 + r) * K + col8;
            ldsp[cc] = &Bs[(ch - 8) * 512];
        }
    }

    f32x4 acc[4][4];
    #pragma unroll
    for (int m = 0; m < 4; ++m)
        #pragma unroll
        for (int n = 0; n < 4; ++n)
            acc[m][n] = (f32x4){0.f, 0.f, 0.f, 0.f};

    for (int k0 = 0; k0 < K; k0 += 32) {
        #pragma unroll
        for (int cc = 0; cc < 4; ++cc)
            __builtin_amdgcn_global_load_lds(
                (const __attribute__((address_space(1))) void*)(srcp[cc] + k0),
                (__attribute__((address_space(3))) void*)ldsp[cc], 16, 0, 0);
        __syncthreads();
        bf16x8 af[4], bfr[4];
        #pragma unroll
        for (int m = 0; m < 4; ++m)
            af[m] = *(bf16x8*)&As[(wr + m * 16 + lr) * 32 + lk];
        #pragma unroll
        for (int n = 0; n < 4; ++n)
            bfr[n] = *(bf16x8*)&Bs[(wc + n * 16 + lr) * 32 + lk];
        #pragma unroll
        for (int m = 0; m < 4; ++m)
            #pragma unroll
            for (int n = 0; n < 4; ++n)
                acc[m][n] = __builtin_amdgcn_mfma_f32_16x16x32_bf16(af[m], bfr[n], acc[m][n], 0, 0, 0);
        __syncthreads();
    }

    int crow = bm + wr + ((lane >> 4) << 2);
    int ccol = bn + wc + (lane & 15);
    #pragma unroll
    for (int n = 0; n < 4; ++n) {
        int col = ccol + n * 16;
        if (col < N) {
            float bv = bias ? bias[col] : 0.f;
            #pragma unroll
            for (int m = 0; m < 4; ++m) {
                #pragma unroll
                for (int j = 0; j < 4; ++j) {
                    int row = crow + m * 16 + j;
                    float v = acc[m][n][j] + bv;
                    if constexpr (CBF) ((u16*)Cv)[(size_t)row * ldc + col] = f2b(v);
                    else               ((float*)Cv)[(size_t)row * ldc + col] = v;
                }
            }
        }
    }
}

// ---------- LayerNorm (in place on bf16 u) ----------
__global__ __launch_bounds__(256) void layernorm_k(u16* __restrict__ u,
                                                   const float* __restrict__ g,
                                                   const float* __restrict__ bt) {
    int row = blockIdx.x;
    u16* p = u + (size_t)row * D_MODELx;
    float v[4]; float s = 0.f;
    #pragma unroll
    for (int i = 0; i < 4; ++i) { v[i] = b2f(p[threadIdx.x + i * 256]); s += v[i]; }
    float mean = block_sum(s) * (1.f / D_MODELx);
    float vs = 0.f;
    #pragma unroll
    for (int i = 0; i < 4; ++i) { float d = v[i] - mean; vs += d * d; }
    float var = block_sum(vs) * (1.f / D_MODELx);
    float inv = rsqrtf(var + 1e-5f);
    #pragma unroll
    for (int i = 0; i < 4; ++i) {
        int c = threadIdx.x + i * 256;
        p[c] = f2b((v[i] - mean) * inv * g[c] + bt[c]);
    }
}

// ---------- dt softplus + per-chunk cumsum: one wave per (b,h,c) ----------
__global__ __launch_bounds__(256) void dt_acs_k(const u16* __restrict__ xb,
                                                const float* __restrict__ dt_bias,
                                                const float* __restrict__ A_log,
                                                float* __restrict__ dtv, float* __restrict__ acs) {
    int gid = blockIdx.x * 4 + (threadIdx.x >> 6);
    int lane = threadIdx.x & 63;
    int c = gid & 31;
    int h = (gid >> 5) & 31;
    int b = gid >> 10;
    float A = -expf(A_log[h]);
    int row = b * LSEQ + c * CHUNKx + lane;
    float x = b2f(xb[(size_t)row * LDX + XB_DT + h]) + dt_bias[h];
    float d = (x > 20.f) ? x : log1pf(expf(x));
    dtv[(size_t)row * NHEADSx + h] = d;
    float v = A * d;
    #pragma unroll
    for (int off = 1; off < 64; off <<= 1) {
        float t = __shfl_up(v, off);
        if (lane >= off) v += t;
    }
    acs[(((size_t)(b * NHEADSx + h)) * NCHUNKx + c) * CHUNKx + lane] = v;
}

// ---------- causal depthwise conv (k=4) + SiLU, in place ----------
__global__ __launch_bounds__(256) void conv_k(u16* __restrict__ xb,
                                              const float* __restrict__ w,
                                              const float* __restrict__ bias) {
    int chl = threadIdx.x & 31, seg = threadIdx.x >> 5;
    int ch = blockIdx.x * 32 + chl;
    int b = blockIdx.y;
    float w0 = w[ch * 4 + 0], w1 = w[ch * 4 + 1], w2 = w[ch * 4 + 2], w3 = w[ch * 4 + 3];
    float bs = bias[ch];
    size_t base = ((size_t)b * LSEQ + seg * 256) * LDX + ch;
    float h0 = 0.f, h1 = 0.f, h2 = 0.f;
    if (seg) {
        h0 = b2f(xb[base - 3 * (size_t)LDX]);
        h1 = b2f(xb[base - 2 * (size_t)LDX]);
        h2 = b2f(xb[base - 1 * (size_t)LDX]);
    }
    __syncthreads();
    for (int i = 0; i < 256; ++i) {
        float xl = b2f(xb[base + (size_t)i * LDX]);
        float o = fmaf(w3, xl, fmaf(w2, h2, fmaf(w1, h1, fmaf(w0, h0, bs))));
        xb[base + (size_t)i * LDX] = f2b(silu_f(o));
        h0 = h1; h1 = h2; h2 = xl;
    }
}

// ---------- fused SSD v2: scale-folded, fused phases, swizzled scatter ----------
// block = (h,b), 512 thr. Per chunk: G=C@B^T and Yoff=C@Sp^T fused (share aC);
// Gp = mask*exp(al-as)*dt[s]*G (dt folded); Bt = (B*dd)^T (dd folded at build);
// Ydiag=Gp@Xt and S+=Bt@Xt fused (share bX). Xt/Bt col-group XOR-swizzled so
// the scalar transpose-scatter writes are conflict-free.
__global__ __launch_bounds__(512) void ssd_k(u16* __restrict__ xb,
                                             const float* __restrict__ dtv,
                                             const float* __restrict__ acs,
                                             const float* __restrict__ Dp) {
    __shared__ u16 Xt[64 * 72];    // xs^T [p][l], col-group swizzled
    __shared__ u16 Bl[64 * 136];   // B [s][n] linear
    __shared__ u16 Bt[128 * 72];   // (B*dd)^T [n][l], col-group swizzled
    __shared__ u16 Cl[64 * 136];   // C [l][n] linear
    __shared__ u16 Gp[64 * 72];    // L*G*dt [l][s] linear
    __shared__ u16 Sp[64 * 136];   // prefix state S [p][n] bf16
    __shared__ float acss[64], eaS[64], dtS[64], ddS[64];
    __shared__ float dcS;

    int h = blockIdx.x, b = blockIdx.y;
    int tid = threadIdx.x;
    int w = tid >> 6, lane = tid & 63, l15 = lane & 15, g = lane >> 4;
    int lt = w >> 1, hf = w & 1;
    float Dh = Dp[h];

    int sr = tid >> 3, scq = tid & 7;      // stage mapping: row, col-chunk
    int srh = sr >> 3, srl = sr & 7;
    int sgrp = ((srh ^ scq) << 3) + srl;   // swizzled col for (l=sr, p-group=scq)

    f32x4 sreg[4];
    #pragma unroll
    for (int pt = 0; pt < 4; ++pt) sreg[pt] = (f32x4){0.f, 0.f, 0.f, 0.f};

    const float* acb = acs + ((size_t)(b * NHEADSx + h)) * NCHUNKx * CHUNKx;

    // zero Sp
    for (int i = tid; i < 64 * 136 / 8; i += 512) ((uint4*)Sp)[i] = (uint4){0, 0, 0, 0};

    // scalars chunk 0
    if (tid < 64) {
        float a = acb[tid];
        float a63 = __shfl(a, 63);
        float d = dtv[(size_t)(b * LSEQ + tid) * NHEADSx + h];
        acss[tid] = a; eaS[tid] = __expf(a); dtS[tid] = d;
        ddS[tid] = d * __expf(a63 - a);
        if (tid == 0) dcS = __expf(a63);
    }
    // stage chunk 0
    uint4 rXs, rB0, rB1, rC0, rC1;
    {
        size_t rowb = ((size_t)(b * LSEQ) + sr) * LDX;
        rXs = *(const uint4*)(xb + rowb + h * 64 + scq * 8);
        rB0 = *(const uint4*)(xb + rowb + XB_B + scq * 8);
        rB1 = *(const uint4*)(xb + rowb + XB_B + 64 + scq * 8);
        rC0 = *(const uint4*)(xb + rowb + XB_C + scq * 8);
        rC1 = *(const uint4*)(xb + rowb + XB_C + 64 + scq * 8);
    }
    __syncthreads();
    {
        *(uint4*)&Bl[sr * 136 + scq * 8] = rB0;
        *(uint4*)&Bl[sr * 136 + 64 + scq * 8] = rB1;
        *(uint4*)&Cl[sr * 136 + scq * 8] = rC0;
        *(uint4*)&Cl[sr * 136 + 64 + scq * 8] = rC1;
        const u16* px = (const u16*)&rXs;
        const u16* pb0 = (const u16*)&rB0;
        const u16* pb1 = (const u16*)&rB1;
        float dd = ddS[sr];
        #pragma unroll
        for (int j = 0; j < 8; ++j) {
            Xt[(scq * 8 + j) * 72 + sgrp] = px[j];
            Bt[(scq * 8 + j) * 72 + sgrp] = f2b(b2f(pb0[j]) * dd);
            Bt[(64 + scq * 8 + j) * 72 + sgrp] = f2b(b2f(pb1[j]) * dd);
        }
    }
    __syncthreads();

    for (int c = 0; c < NCHUNKx; ++c) {
        int row0 = b * LSEQ + c * CHUNKx;
        // issue next-chunk loads early (hide under MFMA)
        if (c + 1 < NCHUNKx) {
            size_t rowb = ((size_t)row0 + CHUNKx + sr) * LDX;
            rXs = *(const uint4*)(xb + rowb + h * 64 + scq * 8);
            rB0 = *(const uint4*)(xb + rowb + XB_B + scq * 8);
            rB1 = *(const uint4*)(xb + rowb + XB_B + 64 + scq * 8);
            rC0 = *(const uint4*)(xb + rowb + XB_C + scq * 8);
            rC1 = *(const uint4*)(xb + rowb + XB_C + 64 + scq * 8);
        }
        // phase A: G = C@B^T and Yoff = C@Sp^T (shared aC)
        f32x4 accG[2], yac[2];
        accG[0] = (f32x4){0.f, 0.f, 0.f, 0.f}; accG[1] = (f32x4){0.f, 0.f, 0.f, 0.f};
        yac[0] = (f32x4){0.f, 0.f, 0.f, 0.f};  yac[1] = (f32x4){0.f, 0.f, 0.f, 0.f};
        #pragma unroll
        for (int kk = 0; kk < 4; ++kk) {
            bf16x8 aC = *(bf16x8*)&Cl[(16 * lt + l15) * 136 + 32 * kk + 8 * g];
            #pragma unroll
            for (int q = 0; q < 2; ++q) {
                int st = 16 * (2 * hf + q) + l15;
                bf16x8 bB = *(bf16x8*)&Bl[st * 136 + 32 * kk + 8 * g];
                accG[q] = __builtin_amdgcn_mfma_f32_16x16x32_bf16(aC, bB, accG[q], 0, 0, 0);
                bf16x8 bS = *(bf16x8*)&Sp[st * 136 + 32 * kk + 8 * g];
                yac[q] = __builtin_amdgcn_mfma_f32_16x16x32_bf16(aC, bS, yac[q], 0, 0, 0);
            }
        }
        // yac *= exp(acs[l]); Gp = mask*exp(al-as)*dt[s]*G; sreg prescale
        float dc = dcS;
        #pragma unroll
        for (int q = 0; q < 2; ++q) {
            int s = 16 * (2 * hf + q) + l15;
            float as = acss[s], ds = dtS[s];
            #pragma unroll
            for (int j = 0; j < 4; ++j) {
                int l = 16 * lt + 4 * g + j;
                yac[q][j] *= eaS[l];
                float v = (s <= l) ? accG[q][j] * __expf(acss[l] - as) * ds : 0.f;
                Gp[l * 72 + s] = f2b(v);
            }
        }
        #pragma unroll
        for (int pt = 0; pt < 4; ++pt)
            #pragma unroll
            for (int j = 0; j < 4; ++j) sreg[pt][j] *= dc;
        __syncthreads();

        // phase B: Ydiag = Gp@Xt and S += Bt@Xt (shared bX)
        #pragma unroll
        for (int kk = 0; kk < 2; ++kk) {
            bf16x8 bX[4];
            #pragma unroll
            for (int pt = 0; pt < 4; ++pt) {
                int row = 16 * pt + l15;
                int grp = (4 * kk + g) ^ ((row >> 3) & 7);
                bX[pt] = *(bf16x8*)&Xt[row * 72 + grp * 8];
            }
            bf16x8 aG = *(bf16x8*)&Gp[(16 * lt + l15) * 72 + 32 * kk + 8 * g];
            #pragma unroll
            for (int q = 0; q < 2; ++q)
                yac[q] = __builtin_amdgcn_mfma_f32_16x16x32_bf16(aG, bX[2 * hf + q], yac[q], 0, 0, 0);
            int rowb = 16 * w + l15;
            int grpb = (4 * kk + g) ^ ((rowb >> 3) & 7);
            bf16x8 aB = *(bf16x8*)&Bt[rowb * 72 + grpb * 8];
            #pragma unroll
            for (int pt = 0; pt < 4; ++pt)
                sreg[pt] = __builtin_amdgcn_mfma_f32_16x16x32_bf16(aB, bX[pt], sreg[pt], 0, 0, 0);
        }
        // epilogue: y = yac + D*xs  (xs read back from swizzled Xt)
        #pragma unroll
        for (int q = 0; q < 2; ++q) {
            int p = 16 * (2 * hf + q) + l15;
            int ph = (p >> 3) & 7;
            #pragma unroll
            for (int j = 0; j < 4; ++j) {
                int l = 16 * lt + 4 * g + j;
                int col = (((l >> 3) ^ ph) << 3) + (l & 7);
                float xsv = b2f(Xt[p * 72 + col]);
                xb[(size_t)(row0 + l) * LDX + h * 64 + p] = f2b(yac[q][j] + Dh * xsv);
            }
        }
        // scalars for chunk c+1 (safe: current scalars only read pre-sync1)
        if (tid < 64 && c + 1 < NCHUNKx) {
            float a = acb[(c + 1) * CHUNKx + tid];
            float a63 = __shfl(a, 63);
            float d = dtv[(size_t)(row0 + CHUNKx + tid) * NHEADSx + h];
            acss[tid] = a; eaS[tid] = __expf(a); dtS[tid] = d;
            ddS[tid] = d * __expf(a63 - a);
            if (tid == 0) dcS = __expf(a63);
        }
        __syncthreads();
        // write Sp; stage writes for c+1
        #pragma unroll
        for (int pt = 0; pt < 4; ++pt) {
            ushort4 pk;
            pk.x = f2b(sreg[pt][0]); pk.y = f2b(sreg[pt][1]);
            pk.z = f2b(sreg[pt][2]); pk.w = f2b(sreg[pt][3]);
            *(ushort4*)&Sp[(16 * pt + l15) * 136 + 16 * w + 4 * g] = pk;
        }
        if (c + 1 < NCHUNKx) {
            *(uint4*)&Bl[sr * 136 + scq * 8] = rB0;
            *(uint4*)&Bl[sr * 136 + 64 + scq * 8] = rB1;
            *(uint4*)&Cl[sr * 136 + scq * 8] = rC0;
            *(uint4*)&Cl[sr * 136 + 64 + scq * 8] = rC1;
            const u16* px = (const u16*)&rXs;
            const u16* pb0 = (const u16*)&rB0;
            const u16* pb1 = (const u16*)&rB1;
            float dd = ddS[sr];
            #pragma unroll
            for (int j = 0; j < 8; ++j) {
                Xt[(scq * 8 + j) * 72 + sgrp] = px[j];
                Bt[(scq * 8 + j) * 72 + sgrp] = f2b(b2f(pb0[j]) * dd);
                Bt[(64 + scq * 8 + j) * 72 + sgrp] = f2b(b2f(pb1[j]) * dd);
            }
        }
        __syncthreads();
    }
}

// ---------- gated RMSNorm in place over y ----------
__global__ __launch_bounds__(256) void rmsgate_k(u16* __restrict__ xb,
                                                 const u16* __restrict__ zb,
                                                 const float* __restrict__ w) {
    int row = blockIdx.x;
    const u16* zp = zb + (size_t)row * D_INNERx;
    u16* yp = xb + (size_t)row * LDX;
    float vals[8];
    float ss = 0.f;
    #pragma unroll
    for (int i = 0; i < 8; ++i) {
        int c = threadIdx.x + i * 256;
        float z = b2f(zp[c]);
        float y = b2f(yp[c]) * silu_f(z);
        vals[i] = y; ss += y * y;
    }
    float tot = block_sum(ss);
    float scale = rsqrtf(tot * (1.f / D_INNERx) + 1e-5f);
    #pragma unroll
    for (int i = 0; i < 8; ++i) {
        int c = threadIdx.x + i * 256;
        yp[c] = f2b(vals[i] * scale * w[c]);
    }
}

// ---------- hidden = out[:, -1, :] ----------
__global__ void hidden_k(float* __restrict__ out) {
    int i = blockIdx.x * blockDim.x + threadIdx.x;
    int b = i >> 10, d = i & 1023;
    out[(size_t)NTOK * D_MODELx + i] = out[((size_t)(b * LSEQ + LSEQ - 1)) * D_MODELx + d];
}

extern "C" void kernel_launch(void* const* d_in, const int* in_sizes, int n_in,
                              void* d_out, int out_size, void* d_ws, size_t ws_size,
                              hipStream_t stream) {
    const float* x       = (const float*)d_in[0];
    const float* Wi      = (const float*)d_in[1];
    const float* bi      = (const float*)d_in[2];
    const float* ln_g    = (const float*)d_in[3];
    const float* ln_b    = (const float*)d_in[4];
    const float* Win     = (const float*)d_in[5];
    const float* conv_w  = (const float*)d_in[6];
    const float* conv_b  = (const float*)d_in[7];
    const float* dt_bias = (const float*)d_in[8];
    const float* A_log   = (const float*)d_in[9];
    const float* Dv      = (const float*)d_in[10];
    const float* rms_w   = (const float*)d_in[11];
    const float* Wout    = (const float*)d_in[12];
    float* out = (float*)d_out;

    if (ws_size < 118489088ull) return;
    u16* xb  = (u16*)d_ws;                                   // [NTOK][LDX] bf16
    u16* ub  = xb + (size_t)NTOK * LDX;                      // [NTOK][1024] bf16
    u16* Woutb = ub;                                         // overlay after y ready
    u16* Rb  = ub + (size_t)NTOK * D_MODELx;
    u16* Wib  = Rb;
    u16* Winb = Rb + (size_t)1024 * 1024;
    float* acs = (float*)Rb;                                 // overlays Wib/Winb after GEMMs
    float* dtv = acs + (size_t)B_N * NHEADSx * NCHUNKx * CHUNKx;
    u16* xbf = xb;
    u16* zb  = (u16*)d_out;

    // 0. conversions
    cvt_f2b_k<<<16384, 256, 0, stream>>>(x, xbf, 16777216 / 4);
    cvt_f2b_k<<<1024, 256, 0, stream>>>(Wi, Wib, 1048576 / 4);
    // 1. u = x @ Wi^T + bi
    gemm_mfma<1><<<dim3(8, 128), 256, 0, stream>>>(
        xbf, Wib, bi, ub, NTOK, D_MODELx, D_INx, D_INx, D_MODELx);
    // 2. LayerNorm
    layernorm_k<<<NTOK, 256, 0, stream>>>(ub, ln_g, ln_b);
    // 3a. z = u @ Win[0:2048]^T -> d_out
    cvt_f2b_k<<<2048, 256, 0, stream>>>(Win, Winb, (2048 * 1024) / 4);
    gemm_mfma<1><<<dim3(16, 128), 256, 0, stream>>>(
        ub, Winb, nullptr, zb, NTOK, D_INNERx, D_MODELx, D_MODELx, D_INNERx);
    // 3b. xBCdt = u @ Win[2048:4384]^T -> xb
    cvt_f2b_k<<<2336, 256, 0, stream>>>(Win + (size_t)2048 * 1024, Winb, (2336 * 1024) / 4);
    gemm_mfma<1><<<dim3(19, 128), 256, 0, stream>>>(
        ub, Winb, nullptr, xb, NTOK, LDX, D_MODELx, D_MODELx, LDX);
    // 4. dt + per-chunk cumsum (wave-parallel scan)
    dt_acs_k<<<2048, 256, 0, stream>>>(xb, dt_bias, A_log, dtv, acs);
    // 5. conv + silu in place
    conv_k<<<dim3(CONV_DIMx / 32, B_N), 256, 0, stream>>>(xb, conv_w, conv_b);
    // 6+7. fused SSD v2
    ssd_k<<<dim3(NHEADSx, B_N), 512, 0, stream>>>(xb, dtv, acs, Dv);
    // 8. gated RMSNorm in place over y
    rmsgate_k<<<NTOK, 256, 0, stream>>>(xb, zb, rms_w);
    // 9. out = yn @ Wout^T
    cvt_f2b_k<<<2048, 256, 0, stream>>>(Wout, Woutb, (2048 * 1024) / 4);
    gemm_mfma<0><<<dim3(8, 128), 256, 0, stream>>>(
        xb, Woutb, nullptr, out, NTOK, D_MODELx, D_INNERx, LDX, D_MODELx);
    // 10. hidden
    hidden_k<<<(B_N * D_MODELx) / 256, 256, 0, stream>>>(out);
}

// Round 6
// 668.097 us; speedup vs baseline: 1.6359x; 1.6359x over previous
//
#include <hip/hip_runtime.h>
#include <math.h>

typedef unsigned short u16;
typedef __attribute__((ext_vector_type(8))) short bf16x8;
typedef __attribute__((ext_vector_type(4))) float f32x4;

#define B_N 8
#define LSEQ 2048
#define D_INx 1024
#define D_MODELx 1024
#define D_STATEx 128
#define D_INNERx 2048
#define NHEADSx 32
#define HEADDIMx 64
#define CONV_DIMx 2304
#define D_IN_PROJx 4384
#define CHUNKx 64
#define NCHUNKx 32
#define NTOK (B_N*LSEQ)   // 16384

#define LDX 2336
#define XB_B 2048
#define XB_C 2176
#define XB_DT 2304

// ---------- bf16 helpers (storage only; math fp32) ----------
__device__ __forceinline__ float b2f(u16 u) {
    return __uint_as_float(((unsigned)u) << 16);
}
__device__ __forceinline__ u16 f2b(float f) {
    unsigned u = __float_as_uint(f);
    return (u16)((u + 0x7FFFu + ((u >> 16) & 1u)) >> 16);  // RNE
}

__device__ __forceinline__ float block_sum(float v) {
    __shared__ float sm[8];
    int lane = threadIdx.x & 63, wid = threadIdx.x >> 6;
    #pragma unroll
    for (int o = 32; o; o >>= 1) v += __shfl_xor(v, o);
    __syncthreads();
    if (lane == 0) sm[wid] = v;
    __syncthreads();
    float r = 0.f;
    int nw = blockDim.x >> 6;
    for (int w = 0; w < nw; ++w) r += sm[w];
    return r;
}

__device__ __forceinline__ float silu_f(float x) {
    return x / (1.f + expf(-x));
}

// ---------- fp32 -> bf16 conversion ----------
__global__ __launch_bounds__(256) void cvt_f2b_k(const float* __restrict__ in,
                                                 u16* __restrict__ out, int n4) {
    int i = blockIdx.x * 256 + threadIdx.x;
    if (i >= n4) return;
    float4 v = ((const float4*)in)[i];
    ushort4 o;
    o.x = f2b(v.x); o.y = f2b(v.y); o.z = f2b(v.z); o.w = f2b(v.w);
    ((ushort4*)out)[i] = o;
}

// ---------- bf16 MFMA GEMM (m97 structure, verified round 3) ----------
template<int CBF>
__global__ __launch_bounds__(256) void gemm_mfma(const u16* __restrict__ A,
                                                 const u16* __restrict__ W,
                                                 const float* __restrict__ bias,
                                                 void* __restrict__ Cv,
                                                 int M, int N, int K, int lda, int ldc) {
    __shared__ u16 As[128 * 32];
    __shared__ u16 Bs[128 * 32];

    int nwgx = gridDim.x;
    int nwg = nwgx * gridDim.y;
    int bid = blockIdx.y * nwgx + blockIdx.x;
    int cpx = nwg >> 3;
    bid = (bid & 7) * cpx + (bid >> 3);
    int bm = (bid / nwgx) * 128;
    int bn = (bid % nwgx) * 128;

    int tid = threadIdx.x, wid = tid >> 6, lane = tid & 63;
    int lr = lane & 15, lk = (lane >> 4) << 3;
    int wr = (wid >> 1) << 6, wc = (wid & 1) << 6;

    const u16* srcp[4];
    u16* ldsp[4];
    #pragma unroll
    for (int cc = 0; cc < 4; ++cc) {
        int ch = wid * 4 + cc;
        int r = lane >> 2, col8 = (lane & 3) << 3;
        if (ch < 8) {
            srcp[cc] = A + (size_t)(bm + ch * 16 + r) * lda + col8;
            ldsp[cc] = &As[ch * 512];
        } else {
            srcp[cc] = W + (size_t)(bn + (ch - 8) * 16 + r) * K + col8;
            ldsp[cc] = &Bs[(ch - 8) * 512];
        }
    }

    f32x4 acc[4][4];
    #pragma unroll
    for (int m = 0; m < 4; ++m)
        #pragma unroll
        for (int n = 0; n < 4; ++n)
            acc[m][n] = (f32x4){0.f, 0.f, 0.f, 0.f};

    for (int k0 = 0; k0 < K; k0 += 32) {
        #pragma unroll
        for (int cc = 0; cc < 4; ++cc)
            __builtin_amdgcn_global_load_lds(
                (const __attribute__((address_space(1))) void*)(srcp[cc] + k0),
                (__attribute__((address_space(3))) void*)ldsp[cc], 16, 0, 0);
        __syncthreads();
        bf16x8 af[4], bfr[4];
        #pragma unroll
        for (int m = 0; m < 4; ++m)
            af[m] = *(bf16x8*)&As[(wr + m * 16 + lr) * 32 + lk];
        #pragma unroll
        for (int n = 0; n < 4; ++n)
            bfr[n] = *(bf16x8*)&Bs[(wc + n * 16 + lr) * 32 + lk];
        #pragma unroll
        for (int m = 0; m < 4; ++m)
            #pragma unroll
            for (int n = 0; n < 4; ++n)
                acc[m][n] = __builtin_amdgcn_mfma_f32_16x16x32_bf16(af[m], bfr[n], acc[m][n], 0, 0, 0);
        __syncthreads();
    }

    int crow = bm + wr + ((lane >> 4) << 2);
    int ccol = bn + wc + (lane & 15);
    #pragma unroll
    for (int n = 0; n < 4; ++n) {
        int col = ccol + n * 16;
        if (col < N) {
            float bv = bias ? bias[col] : 0.f;
            #pragma unroll
            for (int m = 0; m < 4; ++m) {
                #pragma unroll
                for (int j = 0; j < 4; ++j) {
                    int row = crow + m * 16 + j;
                    float v = acc[m][n][j] + bv;
                    if constexpr (CBF) ((u16*)Cv)[(size_t)row * ldc + col] = f2b(v);
                    else               ((float*)Cv)[(size_t)row * ldc + col] = v;
                }
            }
        }
    }
}

// ---------- LayerNorm (in place on bf16 u) ----------
__global__ __launch_bounds__(256) void layernorm_k(u16* __restrict__ u,
                                                   const float* __restrict__ g,
                                                   const float* __restrict__ bt) {
    int row = blockIdx.x;
    u16* p = u + (size_t)row * D_MODELx;
    float v[4]; float s = 0.f;
    #pragma unroll
    for (int i = 0; i < 4; ++i) { v[i] = b2f(p[threadIdx.x + i * 256]); s += v[i]; }
    float mean = block_sum(s) * (1.f / D_MODELx);
    float vs = 0.f;
    #pragma unroll
    for (int i = 0; i < 4; ++i) { float d = v[i] - mean; vs += d * d; }
    float var = block_sum(vs) * (1.f / D_MODELx);
    float inv = rsqrtf(var + 1e-5f);
    #pragma unroll
    for (int i = 0; i < 4; ++i) {
        int c = threadIdx.x + i * 256;
        p[c] = f2b((v[i] - mean) * inv * g[c] + bt[c]);
    }
}

// ---------- dt softplus + per-chunk cumsum: one wave per (b,h,c) ----------
__global__ __launch_bounds__(256) void dt_acs_k(const u16* __restrict__ xb,
                                                const float* __restrict__ dt_bias,
                                                const float* __restrict__ A_log,
                                                float* __restrict__ dtv, float* __restrict__ acs) {
    int gid = blockIdx.x * 4 + (threadIdx.x >> 6);
    int lane = threadIdx.x & 63;
    int c = gid & 31;
    int h = (gid >> 5) & 31;
    int b = gid >> 10;
    float A = -expf(A_log[h]);
    int row = b * LSEQ + c * CHUNKx + lane;
    float x = b2f(xb[(size_t)row * LDX + XB_DT + h]) + dt_bias[h];
    float d = (x > 20.f) ? x : log1pf(expf(x));
    dtv[(size_t)row * NHEADSx + h] = d;
    float v = A * d;
    #pragma unroll
    for (int off = 1; off < 64; off <<= 1) {
        float t = __shfl_up(v, off);
        if (lane >= off) v += t;
    }
    acs[(((size_t)(b * NHEADSx + h)) * NCHUNKx + c) * CHUNKx + lane] = v;
}

// ---------- causal depthwise conv (k=4) + SiLU, in place ----------
__global__ __launch_bounds__(256) void conv_k(u16* __restrict__ xb,
                                              const float* __restrict__ w,
                                              const float* __restrict__ bias) {
    int chl = threadIdx.x & 31, seg = threadIdx.x >> 5;
    int ch = blockIdx.x * 32 + chl;
    int b = blockIdx.y;
    float w0 = w[ch * 4 + 0], w1 = w[ch * 4 + 1], w2 = w[ch * 4 + 2], w3 = w[ch * 4 + 3];
    float bs = bias[ch];
    size_t base = ((size_t)b * LSEQ + seg * 256) * LDX + ch;
    float h0 = 0.f, h1 = 0.f, h2 = 0.f;
    if (seg) {
        h0 = b2f(xb[base - 3 * (size_t)LDX]);
        h1 = b2f(xb[base - 2 * (size_t)LDX]);
        h2 = b2f(xb[base - 1 * (size_t)LDX]);
    }
    __syncthreads();
    for (int i = 0; i < 256; ++i) {
        float xl = b2f(xb[base + (size_t)i * LDX]);
        float o = fmaf(w3, xl, fmaf(w2, h2, fmaf(w1, h1, fmaf(w0, h0, bs))));
        xb[base + (size_t)i * LDX] = f2b(silu_f(o));
        h0 = h1; h1 = h2; h2 = xl;
    }
}

// ---------- fused SSD v3: v2 minus the runtime-indexed bX[] (rule #20 fix) ----------
// block = (h,b), 512 thr. Per chunk: G=C@B^T and Yoff=C@Sp^T fused (share aC);
// Gp = mask*exp(al-as)*dt[s]*G (dt folded); Bt = (B*dd)^T (dd folded at build);
// phase B re-loads each Xt fragment per use (compile-time array indices ONLY).
__global__ __launch_bounds__(512) void ssd_k(u16* __restrict__ xb,
                                             const float* __restrict__ dtv,
                                             const float* __restrict__ acs,
                                             const float* __restrict__ Dp) {
    __shared__ u16 Xt[64 * 72];    // xs^T [p][l], col-group swizzled
    __shared__ u16 Bl[64 * 136];   // B [s][n] linear
    __shared__ u16 Bt[128 * 72];   // (B*dd)^T [n][l], col-group swizzled
    __shared__ u16 Cl[64 * 136];   // C [l][n] linear
    __shared__ u16 Gp[64 * 72];    // L*G*dt [l][s] linear
    __shared__ u16 Sp[64 * 136];   // prefix state S [p][n] bf16
    __shared__ float acss[64], eaS[64], dtS[64], ddS[64];
    __shared__ float dcS;

    int h = blockIdx.x, b = blockIdx.y;
    int tid = threadIdx.x;
    int w = tid >> 6, lane = tid & 63, l15 = lane & 15, g = lane >> 4;
    int lt = w >> 1, hf = w & 1;
    float Dh = Dp[h];

    int sr = tid >> 3, scq = tid & 7;      // stage mapping: row, col-chunk
    int srh = sr >> 3, srl = sr & 7;
    int sgrp = ((srh ^ scq) << 3) + srl;   // swizzled col for (l=sr, p-group=scq)

    f32x4 sreg[4];
    #pragma unroll
    for (int pt = 0; pt < 4; ++pt) sreg[pt] = (f32x4){0.f, 0.f, 0.f, 0.f};

    const float* acb = acs + ((size_t)(b * NHEADSx + h)) * NCHUNKx * CHUNKx;

    // zero Sp
    for (int i = tid; i < 64 * 136 / 8; i += 512) ((uint4*)Sp)[i] = (uint4){0, 0, 0, 0};

    // scalars chunk 0
    if (tid < 64) {
        float a = acb[tid];
        float a63 = __shfl(a, 63);
        float d = dtv[(size_t)(b * LSEQ + tid) * NHEADSx + h];
        acss[tid] = a; eaS[tid] = __expf(a); dtS[tid] = d;
        ddS[tid] = d * __expf(a63 - a);
        if (tid == 0) dcS = __expf(a63);
    }
    // stage chunk 0
    uint4 rXs, rB0, rB1, rC0, rC1;
    {
        size_t rowb = ((size_t)(b * LSEQ) + sr) * LDX;
        rXs = *(const uint4*)(xb + rowb + h * 64 + scq * 8);
        rB0 = *(const uint4*)(xb + rowb + XB_B + scq * 8);
        rB1 = *(const uint4*)(xb + rowb + XB_B + 64 + scq * 8);
        rC0 = *(const uint4*)(xb + rowb + XB_C + scq * 8);
        rC1 = *(const uint4*)(xb + rowb + XB_C + 64 + scq * 8);
    }
    __syncthreads();
    {
        *(uint4*)&Bl[sr * 136 + scq * 8] = rB0;
        *(uint4*)&Bl[sr * 136 + 64 + scq * 8] = rB1;
        *(uint4*)&Cl[sr * 136 + scq * 8] = rC0;
        *(uint4*)&Cl[sr * 136 + 64 + scq * 8] = rC1;
        const u16* px = (const u16*)&rXs;
        const u16* pb0 = (const u16*)&rB0;
        const u16* pb1 = (const u16*)&rB1;
        float dd = ddS[sr];
        #pragma unroll
        for (int j = 0; j < 8; ++j) {
            Xt[(scq * 8 + j) * 72 + sgrp] = px[j];
            Bt[(scq * 8 + j) * 72 + sgrp] = f2b(b2f(pb0[j]) * dd);
            Bt[(64 + scq * 8 + j) * 72 + sgrp] = f2b(b2f(pb1[j]) * dd);
        }
    }
    __syncthreads();

    for (int c = 0; c < NCHUNKx; ++c) {
        int row0 = b * LSEQ + c * CHUNKx;
        // issue next-chunk loads early (hide under MFMA)
        if (c + 1 < NCHUNKx) {
            size_t rowb = ((size_t)row0 + CHUNKx + sr) * LDX;
            rXs = *(const uint4*)(xb + rowb + h * 64 + scq * 8);
            rB0 = *(const uint4*)(xb + rowb + XB_B + scq * 8);
            rB1 = *(const uint4*)(xb + rowb + XB_B + 64 + scq * 8);
            rC0 = *(const uint4*)(xb + rowb + XB_C + scq * 8);
            rC1 = *(const uint4*)(xb + rowb + XB_C + 64 + scq * 8);
        }
        // phase A: G = C@B^T and Yoff = C@Sp^T (shared aC)
        f32x4 accG[2], yac[2];
        accG[0] = (f32x4){0.f, 0.f, 0.f, 0.f}; accG[1] = (f32x4){0.f, 0.f, 0.f, 0.f};
        yac[0] = (f32x4){0.f, 0.f, 0.f, 0.f};  yac[1] = (f32x4){0.f, 0.f, 0.f, 0.f};
        #pragma unroll
        for (int kk = 0; kk < 4; ++kk) {
            bf16x8 aC = *(bf16x8*)&Cl[(16 * lt + l15) * 136 + 32 * kk + 8 * g];
            #pragma unroll
            for (int q = 0; q < 2; ++q) {
                int st = 16 * (2 * hf + q) + l15;
                bf16x8 bB = *(bf16x8*)&Bl[st * 136 + 32 * kk + 8 * g];
                accG[q] = __builtin_amdgcn_mfma_f32_16x16x32_bf16(aC, bB, accG[q], 0, 0, 0);
                bf16x8 bS = *(bf16x8*)&Sp[st * 136 + 32 * kk + 8 * g];
                yac[q] = __builtin_amdgcn_mfma_f32_16x16x32_bf16(aC, bS, yac[q], 0, 0, 0);
            }
        }
        // yac *= exp(acs[l]); Gp = mask*exp(al-as)*dt[s]*G; sreg prescale
        float dc = dcS;
        #pragma unroll
        for (int q = 0; q < 2; ++q) {
            int s = 16 * (2 * hf + q) + l15;
            float as = acss[s], ds = dtS[s];
            #pragma unroll
            for (int j = 0; j < 4; ++j) {
                int l = 16 * lt + 4 * g + j;
                yac[q][j] *= eaS[l];
                float v = (s <= l) ? accG[q][j] * __expf(acss[l] - as) * ds : 0.f;
                Gp[l * 72 + s] = f2b(v);
            }
        }
        #pragma unroll
        for (int pt = 0; pt < 4; ++pt)
            #pragma unroll
            for (int j = 0; j < 4; ++j) sreg[pt][j] *= dc;
        __syncthreads();

        // phase B: Ydiag = Gp@Xt and S += Bt@Xt.
        // All LDS fragments loaded per-use into NAMED vars; array subscripts
        // (yac[q], sreg[pt]) are compile-time only (rule #20).
        #pragma unroll
        for (int kk = 0; kk < 2; ++kk) {
            bf16x8 aG = *(bf16x8*)&Gp[(16 * lt + l15) * 72 + 32 * kk + 8 * g];
            #pragma unroll
            for (int q = 0; q < 2; ++q) {
                int row = 16 * (2 * hf + q) + l15;           // runtime address: OK
                int grp = (4 * kk + g) ^ ((row >> 3) & 7);
                bf16x8 bXq = *(bf16x8*)&Xt[row * 72 + grp * 8];
                yac[q] = __builtin_amdgcn_mfma_f32_16x16x32_bf16(aG, bXq, yac[q], 0, 0, 0);
            }
            int rowb = 16 * w + l15;
            int grpb = (4 * kk + g) ^ ((rowb >> 3) & 7);
            bf16x8 aB = *(bf16x8*)&Bt[rowb * 72 + grpb * 8];
            #pragma unroll
            for (int pt = 0; pt < 4; ++pt) {
                int row = 16 * pt + l15;
                int grp = (4 * kk + g) ^ ((row >> 3) & 7);
                bf16x8 bX = *(bf16x8*)&Xt[row * 72 + grp * 8];
                sreg[pt] = __builtin_amdgcn_mfma_f32_16x16x32_bf16(aB, bX, sreg[pt], 0, 0, 0);
            }
        }
        // epilogue: y = yac + D*xs  (xs read back from swizzled Xt)
        #pragma unroll
        for (int q = 0; q < 2; ++q) {
            int p = 16 * (2 * hf + q) + l15;
            int ph = (p >> 3) & 7;
            #pragma unroll
            for (int j = 0; j < 4; ++j) {
                int l = 16 * lt + 4 * g + j;
                int col = (((l >> 3) ^ ph) << 3) + (l & 7);
                float xsv = b2f(Xt[p * 72 + col]);
                xb[(size_t)(row0 + l) * LDX + h * 64 + p] = f2b(yac[q][j] + Dh * xsv);
            }
        }
        // scalars for chunk c+1 (old values dead after phase A)
        if (tid < 64 && c + 1 < NCHUNKx) {
            float a = acb[(c + 1) * CHUNKx + tid];
            float a63 = __shfl(a, 63);
            float d = dtv[(size_t)(row0 + CHUNKx + tid) * NHEADSx + h];
            acss[tid] = a; eaS[tid] = __expf(a); dtS[tid] = d;
            ddS[tid] = d * __expf(a63 - a);
            if (tid == 0) dcS = __expf(a63);
        }
        __syncthreads();
        // write Sp; stage writes for c+1
        #pragma unroll
        for (int pt = 0; pt < 4; ++pt) {
            ushort4 pk;
            pk.x = f2b(sreg[pt][0]); pk.y = f2b(sreg[pt][1]);
            pk.z = f2b(sreg[pt][2]); pk.w = f2b(sreg[pt][3]);
            *(ushort4*)&Sp[(16 * pt + l15) * 136 + 16 * w + 4 * g] = pk;
        }
        if (c + 1 < NCHUNKx) {
            *(uint4*)&Bl[sr * 136 + scq * 8] = rB0;
            *(uint4*)&Bl[sr * 136 + 64 + scq * 8] = rB1;
            *(uint4*)&Cl[sr * 136 + scq * 8] = rC0;
            *(uint4*)&Cl[sr * 136 + 64 + scq * 8] = rC1;
            const u16* px = (const u16*)&rXs;
            const u16* pb0 = (const u16*)&rB0;
            const u16* pb1 = (const u16*)&rB1;
            float dd = ddS[sr];
            #pragma unroll
            for (int j = 0; j < 8; ++j) {
                Xt[(scq * 8 + j) * 72 + sgrp] = px[j];
                Bt[(scq * 8 + j) * 72 + sgrp] = f2b(b2f(pb0[j]) * dd);
                Bt[(64 + scq * 8 + j) * 72 + sgrp] = f2b(b2f(pb1[j]) * dd);
            }
        }
        __syncthreads();
    }
}

// ---------- gated RMSNorm in place over y ----------
__global__ __launch_bounds__(256) void rmsgate_k(u16* __restrict__ xb,
                                                 const u16* __restrict__ zb,
                                                 const float* __restrict__ w) {
    int row = blockIdx.x;
    const u16* zp = zb + (size_t)row * D_INNERx;
    u16* yp = xb + (size_t)row * LDX;
    float vals[8];
    float ss = 0.f;
    #pragma unroll
    for (int i = 0; i < 8; ++i) {
        int c = threadIdx.x + i * 256;
        float z = b2f(zp[c]);
        float y = b2f(yp[c]) * silu_f(z);
        vals[i] = y; ss += y * y;
    }
    float tot = block_sum(ss);
    float scale = rsqrtf(tot * (1.f / D_INNERx) + 1e-5f);
    #pragma unroll
    for (int i = 0; i < 8; ++i) {
        int c = threadIdx.x + i * 256;
        yp[c] = f2b(vals[i] * scale * w[c]);
    }
}

// ---------- hidden = out[:, -1, :] ----------
__global__ void hidden_k(float* __restrict__ out) {
    int i = blockIdx.x * blockDim.x + threadIdx.x;
    int b = i >> 10, d = i & 1023;
    out[(size_t)NTOK * D_MODELx + i] = out[((size_t)(b * LSEQ + LSEQ - 1)) * D_MODELx + d];
}

extern "C" void kernel_launch(void* const* d_in, const int* in_sizes, int n_in,
                              void* d_out, int out_size, void* d_ws, size_t ws_size,
                              hipStream_t stream) {
    const float* x       = (const float*)d_in[0];
    const float* Wi      = (const float*)d_in[1];
    const float* bi      = (const float*)d_in[2];
    const float* ln_g    = (const float*)d_in[3];
    const float* ln_b    = (const float*)d_in[4];
    const float* Win     = (const float*)d_in[5];
    const float* conv_w  = (const float*)d_in[6];
    const float* conv_b  = (const float*)d_in[7];
    const float* dt_bias = (const float*)d_in[8];
    const float* A_log   = (const float*)d_in[9];
    const float* Dv      = (const float*)d_in[10];
    const float* rms_w   = (const float*)d_in[11];
    const float* Wout    = (const float*)d_in[12];
    float* out = (float*)d_out;

    if (ws_size < 118489088ull) return;
    u16* xb  = (u16*)d_ws;                                   // [NTOK][LDX] bf16
    u16* ub  = xb + (size_t)NTOK * LDX;                      // [NTOK][1024] bf16
    u16* Woutb = ub;                                         // overlay after y ready
    u16* Rb  = ub + (size_t)NTOK * D_MODELx;
    u16* Wib  = Rb;
    u16* Winb = Rb + (size_t)1024 * 1024;
    float* acs = (float*)Rb;                                 // overlays Wib/Winb after GEMMs
    float* dtv = acs + (size_t)B_N * NHEADSx * NCHUNKx * CHUNKx;
    u16* xbf = xb;
    u16* zb  = (u16*)d_out;

    // 0. conversions
    cvt_f2b_k<<<16384, 256, 0, stream>>>(x, xbf, 16777216 / 4);
    cvt_f2b_k<<<1024, 256, 0, stream>>>(Wi, Wib, 1048576 / 4);
    // 1. u = x @ Wi^T + bi
    gemm_mfma<1><<<dim3(8, 128), 256, 0, stream>>>(
        xbf, Wib, bi, ub, NTOK, D_MODELx, D_INx, D_INx, D_MODELx);
    // 2. LayerNorm
    layernorm_k<<<NTOK, 256, 0, stream>>>(ub, ln_g, ln_b);
    // 3a. z = u @ Win[0:2048]^T -> d_out
    cvt_f2b_k<<<2048, 256, 0, stream>>>(Win, Winb, (2048 * 1024) / 4);
    gemm_mfma<1><<<dim3(16, 128), 256, 0, stream>>>(
        ub, Winb, nullptr, zb, NTOK, D_INNERx, D_MODELx, D_MODELx, D_INNERx);
    // 3b. xBCdt = u @ Win[2048:4384]^T -> xb
    cvt_f2b_k<<<2336, 256, 0, stream>>>(Win + (size_t)2048 * 1024, Winb, (2336 * 1024) / 4);
    gemm_mfma<1><<<dim3(19, 128), 256, 0, stream>>>(
        ub, Winb, nullptr, xb, NTOK, LDX, D_MODELx, D_MODELx, LDX);
    // 4. dt + per-chunk cumsum (wave-parallel scan)
    dt_acs_k<<<2048, 256, 0, stream>>>(xb, dt_bias, A_log, dtv, acs);
    // 5. conv + silu in place
    conv_k<<<dim3(CONV_DIMx / 32, B_N), 256, 0, stream>>>(xb, conv_w, conv_b);
    // 6+7. fused SSD v3
    ssd_k<<<dim3(NHEADSx, B_N), 512, 0, stream>>>(xb, dtv, acs, Dv);
    // 8. gated RMSNorm in place over y
    rmsgate_k<<<NTOK, 256, 0, stream>>>(xb, zb, rms_w);
    // 9. out = yn @ Wout^T
    cvt_f2b_k<<<2048, 256, 0, stream>>>(Wout, Woutb, (2048 * 1024) / 4);
    gemm_mfma<0><<<dim3(8, 128), 256, 0, stream>>>(
        xb, Woutb, nullptr, out, NTOK, D_MODELx, D_INNERx, LDX, D_MODELx);
    // 10. hidden
    hidden_k<<<(B_N * D_MODELx) / 256, 256, 0, stream>>>(out);
}

// Round 7
// 582.568 us; speedup vs baseline: 1.8761x; 1.1468x over previous
//
#include <hip/hip_runtime.h>
#include <math.h>

typedef unsigned short u16;
typedef __attribute__((ext_vector_type(8))) short bf16x8;
typedef __attribute__((ext_vector_type(4))) float f32x4;

#define B_N 8
#define LSEQ 2048
#define D_INx 1024
#define D_MODELx 1024
#define D_STATEx 128
#define D_INNERx 2048
#define NHEADSx 32
#define HEADDIMx 64
#define CONV_DIMx 2304
#define D_IN_PROJx 4384
#define CHUNKx 64
#define NCHUNKx 32
#define NTOK (B_N*LSEQ)   // 16384

#define LDX 2336
#define XB_B 2048
#define XB_C 2176
#define XB_DT 2304

// ---------- bf16 helpers (storage only; math fp32) ----------
__device__ __forceinline__ float b2f(u16 u) {
    return __uint_as_float(((unsigned)u) << 16);
}
__device__ __forceinline__ u16 f2b(float f) {
    unsigned u = __float_as_uint(f);
    return (u16)((u + 0x7FFFu + ((u >> 16) & 1u)) >> 16);  // RNE
}

__device__ __forceinline__ float block_sum(float v) {
    __shared__ float sm[8];
    int lane = threadIdx.x & 63, wid = threadIdx.x >> 6;
    #pragma unroll
    for (int o = 32; o; o >>= 1) v += __shfl_xor(v, o);
    __syncthreads();
    if (lane == 0) sm[wid] = v;
    __syncthreads();
    float r = 0.f;
    int nw = blockDim.x >> 6;
    for (int w = 0; w < nw; ++w) r += sm[w];
    return r;
}

__device__ __forceinline__ float silu_f(float x) {
    return x / (1.f + expf(-x));
}

// ---------- fp32 -> bf16 conversion ----------
__global__ __launch_bounds__(256) void cvt_f2b_k(const float* __restrict__ in,
                                                 u16* __restrict__ out, int n4) {
    int i = blockIdx.x * 256 + threadIdx.x;
    if (i >= n4) return;
    float4 v = ((const float4*)in)[i];
    ushort4 o;
    o.x = f2b(v.x); o.y = f2b(v.y); o.z = f2b(v.z); o.w = f2b(v.w);
    ((ushort4*)out)[i] = o;
}

// ---------- bf16 MFMA GEMM v2: 256x256 tile, BK=64, 8 waves, dbuf + counted vmcnt ----------
// C[M,N] = A[M,K] @ W[N,K]^T (+bias). M%256==0, K%64==0, nt=K/64 >= 2.
// W must be row-padded to next multiple of 256 rows; ragged N handled by
// predicated C-write. LDS chunk-XOR swizzle (slot = chunk ^ (row&7)) applied
// via pre-swizzled GLOBAL source (linear gload_lds dest) + swizzled ds_read.
template<int CBF>
__global__ __launch_bounds__(512) void gemm_big(const u16* __restrict__ A,
                                                const u16* __restrict__ W,
                                                const float* __restrict__ bias,
                                                void* __restrict__ Cv,
                                                int M, int N, int K, int lda, int ldc) {
    __shared__ u16 lds[65536];   // [2 buf][A 16384 | B 16384] u16 = 128 KiB

    int nwgx = gridDim.x;
    int nwg = nwgx * gridDim.y;
    int bid = blockIdx.y * nwgx + blockIdx.x;
    int cpx = nwg >> 3;                        // grids here always %8==0
    bid = (bid & 7) * cpx + (bid >> 3);
    int bm = (bid / nwgx) * 256;
    int bn = (bid % nwgx) * 256;

    int tid = threadIdx.x, wid = tid >> 6, lane = tid & 63;
    int wm = wid >> 2, wn = wid & 3;           // 2 x 4 wave grid
    int lr = lane & 15, g = lane >> 4;

    // staging: wave wid stages rows [wid*32, wid*32+32) of A-tile and B-tile,
    // as 4 segments of 8 rows (1024B each, linear LDS dest = wave base + lane*16).
    // lane -> (row = +lane>>3, slot = lane&7); global chunk = slot ^ (row&7).
    int srow = wid * 32 + (lane >> 3);
    int chnk = (lane & 7) ^ (srow & 7);
    const u16* sA = A + (size_t)(bm + srow) * lda + chnk * 8;
    const u16* sB = W + (size_t)(bn + srow) * (size_t)K + chnk * 8;

    f32x4 acc[8][4];
    #pragma unroll
    for (int m = 0; m < 8; ++m)
        #pragma unroll
        for (int n = 0; n < 4; ++n) acc[m][n] = (f32x4){0.f, 0.f, 0.f, 0.f};

    int nt = K >> 6;

#define STAGE_(bf, kt) { \
    u16* da = &lds[(bf) * 32768 + wid * 32 * 64]; \
    u16* db = da + 16384; \
    const u16* ga = sA + (size_t)(kt) * 64; \
    const u16* gb = sB + (size_t)(kt) * 64; \
    _Pragma("unroll") \
    for (int s_ = 0; s_ < 4; ++s_) { \
        __builtin_amdgcn_global_load_lds( \
            (const __attribute__((address_space(1))) void*)(ga + (size_t)(s_ * 8) * lda), \
            (__attribute__((address_space(3))) void*)(da + s_ * 8 * 64), 16, 0, 0); \
        __builtin_amdgcn_global_load_lds( \
            (const __attribute__((address_space(1))) void*)(gb + (size_t)(s_ * 8) * (size_t)K), \
            (__attribute__((address_space(3))) void*)(db + s_ * 8 * 64), 16, 0, 0); \
    } }

    STAGE_(0, 0);
    STAGE_(1, 1);

    for (int t = 0; t < nt; ++t) {
        // counted wait: all but the newest 8 loads (next tile) done -> this buf ready
        if (t + 1 < nt) { asm volatile("s_waitcnt vmcnt(8)" ::: "memory"); }
        else            { asm volatile("s_waitcnt vmcnt(0)" ::: "memory"); }
        __builtin_amdgcn_s_barrier();
        const u16* As_ = &lds[(t & 1) * 32768];
        const u16* Bs_ = As_ + 16384;
        __builtin_amdgcn_s_setprio(1);
        #pragma unroll
        for (int kk = 0; kk < 2; ++kk) {
            int ck8 = (((kk * 4 + g) ^ (lr & 7)) << 3);
            bf16x8 af[8], bfr[4];
            #pragma unroll
            for (int n = 0; n < 4; ++n)
                bfr[n] = *(bf16x8*)&Bs_[(wn * 64 + n * 16 + lr) * 64 + ck8];
            #pragma unroll
            for (int m = 0; m < 8; ++m)
                af[m] = *(bf16x8*)&As_[(wm * 128 + m * 16 + lr) * 64 + ck8];
            #pragma unroll
            for (int m = 0; m < 8; ++m)
                #pragma unroll
                for (int n = 0; n < 4; ++n)
                    acc[m][n] = __builtin_amdgcn_mfma_f32_16x16x32_bf16(af[m], bfr[n], acc[m][n], 0, 0, 0);
        }
        __builtin_amdgcn_s_setprio(0);
        __builtin_amdgcn_s_barrier();
        if (t + 2 < nt) STAGE_((t & 1), t + 2);
    }
#undef STAGE_

    // epilogue: C-write (predicated on col < N)
    int crow = bm + wm * 128 + (g << 2);
    int ccol = bn + wn * 64 + lr;
    #pragma unroll
    for (int n = 0; n < 4; ++n) {
        int col = ccol + n * 16;
        if (col < N) {
            float bv = bias ? bias[col] : 0.f;
            #pragma unroll
            for (int m = 0; m < 8; ++m) {
                #pragma unroll
                for (int j = 0; j < 4; ++j) {
                    int row = crow + m * 16 + j;
                    float v = acc[m][n][j] + bv;
                    if constexpr (CBF) ((u16*)Cv)[(size_t)row * ldc + col] = f2b(v);
                    else               ((float*)Cv)[(size_t)row * ldc + col] = v;
                }
            }
        }
    }
}

// ---------- LayerNorm (in place on bf16 u) ----------
__global__ __launch_bounds__(256) void layernorm_k(u16* __restrict__ u,
                                                   const float* __restrict__ g,
                                                   const float* __restrict__ bt) {
    int row = blockIdx.x;
    u16* p = u + (size_t)row * D_MODELx;
    float v[4]; float s = 0.f;
    #pragma unroll
    for (int i = 0; i < 4; ++i) { v[i] = b2f(p[threadIdx.x + i * 256]); s += v[i]; }
    float mean = block_sum(s) * (1.f / D_MODELx);
    float vs = 0.f;
    #pragma unroll
    for (int i = 0; i < 4; ++i) { float d = v[i] - mean; vs += d * d; }
    float var = block_sum(vs) * (1.f / D_MODELx);
    float inv = rsqrtf(var + 1e-5f);
    #pragma unroll
    for (int i = 0; i < 4; ++i) {
        int c = threadIdx.x + i * 256;
        p[c] = f2b((v[i] - mean) * inv * g[c] + bt[c]);
    }
}

// ---------- dt softplus + per-chunk cumsum: one wave per (b,h,c) ----------
__global__ __launch_bounds__(256) void dt_acs_k(const u16* __restrict__ xb,
                                                const float* __restrict__ dt_bias,
                                                const float* __restrict__ A_log,
                                                float* __restrict__ dtv, float* __restrict__ acs) {
    int gid = blockIdx.x * 4 + (threadIdx.x >> 6);
    int lane = threadIdx.x & 63;
    int c = gid & 31;
    int h = (gid >> 5) & 31;
    int b = gid >> 10;
    float A = -expf(A_log[h]);
    int row = b * LSEQ + c * CHUNKx + lane;
    float x = b2f(xb[(size_t)row * LDX + XB_DT + h]) + dt_bias[h];
    float d = (x > 20.f) ? x : log1pf(expf(x));
    dtv[(size_t)row * NHEADSx + h] = d;
    float v = A * d;
    #pragma unroll
    for (int off = 1; off < 64; off <<= 1) {
        float t = __shfl_up(v, off);
        if (lane >= off) v += t;
    }
    acs[(((size_t)(b * NHEADSx + h)) * NCHUNKx + c) * CHUNKx + lane] = v;
}

// ---------- causal depthwise conv (k=4) + SiLU, in place ----------
__global__ __launch_bounds__(256) void conv_k(u16* __restrict__ xb,
                                              const float* __restrict__ w,
                                              const float* __restrict__ bias) {
    int chl = threadIdx.x & 31, seg = threadIdx.x >> 5;
    int ch = blockIdx.x * 32 + chl;
    int b = blockIdx.y;
    float w0 = w[ch * 4 + 0], w1 = w[ch * 4 + 1], w2 = w[ch * 4 + 2], w3 = w[ch * 4 + 3];
    float bs = bias[ch];
    size_t base = ((size_t)b * LSEQ + seg * 256) * LDX + ch;
    float h0 = 0.f, h1 = 0.f, h2 = 0.f;
    if (seg) {
        h0 = b2f(xb[base - 3 * (size_t)LDX]);
        h1 = b2f(xb[base - 2 * (size_t)LDX]);
        h2 = b2f(xb[base - 1 * (size_t)LDX]);
    }
    __syncthreads();
    for (int i = 0; i < 256; ++i) {
        float xl = b2f(xb[base + (size_t)i * LDX]);
        float o = fmaf(w3, xl, fmaf(w2, h2, fmaf(w1, h1, fmaf(w0, h0, bs))));
        xb[base + (size_t)i * LDX] = f2b(silu_f(o));
        h0 = h1; h1 = h2; h2 = xl;
    }
}

// ---------- fused SSD v3 (verified round 6) ----------
__global__ __launch_bounds__(512) void ssd_k(u16* __restrict__ xb,
                                             const float* __restrict__ dtv,
                                             const float* __restrict__ acs,
                                             const float* __restrict__ Dp) {
    __shared__ u16 Xt[64 * 72];    // xs^T [p][l], col-group swizzled
    __shared__ u16 Bl[64 * 136];   // B [s][n] linear
    __shared__ u16 Bt[128 * 72];   // (B*dd)^T [n][l], col-group swizzled
    __shared__ u16 Cl[64 * 136];   // C [l][n] linear
    __shared__ u16 Gp[64 * 72];    // L*G*dt [l][s] linear
    __shared__ u16 Sp[64 * 136];   // prefix state S [p][n] bf16
    __shared__ float acss[64], eaS[64], dtS[64], ddS[64];
    __shared__ float dcS;

    int h = blockIdx.x, b = blockIdx.y;
    int tid = threadIdx.x;
    int w = tid >> 6, lane = tid & 63, l15 = lane & 15, g = lane >> 4;
    int lt = w >> 1, hf = w & 1;
    float Dh = Dp[h];

    int sr = tid >> 3, scq = tid & 7;
    int srh = sr >> 3, srl = sr & 7;
    int sgrp = ((srh ^ scq) << 3) + srl;

    f32x4 sreg[4];
    #pragma unroll
    for (int pt = 0; pt < 4; ++pt) sreg[pt] = (f32x4){0.f, 0.f, 0.f, 0.f};

    const float* acb = acs + ((size_t)(b * NHEADSx + h)) * NCHUNKx * CHUNKx;

    for (int i = tid; i < 64 * 136 / 8; i += 512) ((uint4*)Sp)[i] = (uint4){0, 0, 0, 0};

    if (tid < 64) {
        float a = acb[tid];
        float a63 = __shfl(a, 63);
        float d = dtv[(size_t)(b * LSEQ + tid) * NHEADSx + h];
        acss[tid] = a; eaS[tid] = __expf(a); dtS[tid] = d;
        ddS[tid] = d * __expf(a63 - a);
        if (tid == 0) dcS = __expf(a63);
    }
    uint4 rXs, rB0, rB1, rC0, rC1;
    {
        size_t rowb = ((size_t)(b * LSEQ) + sr) * LDX;
        rXs = *(const uint4*)(xb + rowb + h * 64 + scq * 8);
        rB0 = *(const uint4*)(xb + rowb + XB_B + scq * 8);
        rB1 = *(const uint4*)(xb + rowb + XB_B + 64 + scq * 8);
        rC0 = *(const uint4*)(xb + rowb + XB_C + scq * 8);
        rC1 = *(const uint4*)(xb + rowb + XB_C + 64 + scq * 8);
    }
    __syncthreads();
    {
        *(uint4*)&Bl[sr * 136 + scq * 8] = rB0;
        *(uint4*)&Bl[sr * 136 + 64 + scq * 8] = rB1;
        *(uint4*)&Cl[sr * 136 + scq * 8] = rC0;
        *(uint4*)&Cl[sr * 136 + 64 + scq * 8] = rC1;
        const u16* px = (const u16*)&rXs;
        const u16* pb0 = (const u16*)&rB0;
        const u16* pb1 = (const u16*)&rB1;
        float dd = ddS[sr];
        #pragma unroll
        for (int j = 0; j < 8; ++j) {
            Xt[(scq * 8 + j) * 72 + sgrp] = px[j];
            Bt[(scq * 8 + j) * 72 + sgrp] = f2b(b2f(pb0[j]) * dd);
            Bt[(64 + scq * 8 + j) * 72 + sgrp] = f2b(b2f(pb1[j]) * dd);
        }
    }
    __syncthreads();

    for (int c = 0; c < NCHUNKx; ++c) {
        int row0 = b * LSEQ + c * CHUNKx;
        if (c + 1 < NCHUNKx) {
            size_t rowb = ((size_t)row0 + CHUNKx + sr) * LDX;
            rXs = *(const uint4*)(xb + rowb + h * 64 + scq * 8);
            rB0 = *(const uint4*)(xb + rowb + XB_B + scq * 8);
            rB1 = *(const uint4*)(xb + rowb + XB_B + 64 + scq * 8);
            rC0 = *(const uint4*)(xb + rowb + XB_C + scq * 8);
            rC1 = *(const uint4*)(xb + rowb + XB_C + 64 + scq * 8);
        }
        f32x4 accG[2], yac[2];
        accG[0] = (f32x4){0.f, 0.f, 0.f, 0.f}; accG[1] = (f32x4){0.f, 0.f, 0.f, 0.f};
        yac[0] = (f32x4){0.f, 0.f, 0.f, 0.f};  yac[1] = (f32x4){0.f, 0.f, 0.f, 0.f};
        #pragma unroll
        for (int kk = 0; kk < 4; ++kk) {
            bf16x8 aC = *(bf16x8*)&Cl[(16 * lt + l15) * 136 + 32 * kk + 8 * g];
            #pragma unroll
            for (int q = 0; q < 2; ++q) {
                int st = 16 * (2 * hf + q) + l15;
                bf16x8 bB = *(bf16x8*)&Bl[st * 136 + 32 * kk + 8 * g];
                accG[q] = __builtin_amdgcn_mfma_f32_16x16x32_bf16(aC, bB, accG[q], 0, 0, 0);
                bf16x8 bS = *(bf16x8*)&Sp[st * 136 + 32 * kk + 8 * g];
                yac[q] = __builtin_amdgcn_mfma_f32_16x16x32_bf16(aC, bS, yac[q], 0, 0, 0);
            }
        }
        float dc = dcS;
        #pragma unroll
        for (int q = 0; q < 2; ++q) {
            int s = 16 * (2 * hf + q) + l15;
            float as = acss[s], ds = dtS[s];
            #pragma unroll
            for (int j = 0; j < 4; ++j) {
                int l = 16 * lt + 4 * g + j;
                yac[q][j] *= eaS[l];
                float v = (s <= l) ? accG[q][j] * __expf(acss[l] - as) * ds : 0.f;
                Gp[l * 72 + s] = f2b(v);
            }
        }
        #pragma unroll
        for (int pt = 0; pt < 4; ++pt)
            #pragma unroll
            for (int j = 0; j < 4; ++j) sreg[pt][j] *= dc;
        __syncthreads();

        #pragma unroll
        for (int kk = 0; kk < 2; ++kk) {
            bf16x8 aG = *(bf16x8*)&Gp[(16 * lt + l15) * 72 + 32 * kk + 8 * g];
            #pragma unroll
            for (int q = 0; q < 2; ++q) {
                int row = 16 * (2 * hf + q) + l15;
                int grp = (4 * kk + g) ^ ((row >> 3) & 7);
                bf16x8 bXq = *(bf16x8*)&Xt[row * 72 + grp * 8];
                yac[q] = __builtin_amdgcn_mfma_f32_16x16x32_bf16(aG, bXq, yac[q], 0, 0, 0);
            }
            int rowb = 16 * w + l15;
            int grpb = (4 * kk + g) ^ ((rowb >> 3) & 7);
            bf16x8 aB = *(bf16x8*)&Bt[rowb * 72 + grpb * 8];
            #pragma unroll
            for (int pt = 0; pt < 4; ++pt) {
                int row = 16 * pt + l15;
                int grp = (4 * kk + g) ^ ((row >> 3) & 7);
                bf16x8 bX = *(bf16x8*)&Xt[row * 72 + grp * 8];
                sreg[pt] = __builtin_amdgcn_mfma_f32_16x16x32_bf16(aB, bX, sreg[pt], 0, 0, 0);
            }
        }
        #pragma unroll
        for (int q = 0; q < 2; ++q) {
            int p = 16 * (2 * hf + q) + l15;
            int ph = (p >> 3) & 7;
            #pragma unroll
            for (int j = 0; j < 4; ++j) {
                int l = 16 * lt + 4 * g + j;
                int col = (((l >> 3) ^ ph) << 3) + (l & 7);
                float xsv = b2f(Xt[p * 72 + col]);
                xb[(size_t)(row0 + l) * LDX + h * 64 + p] = f2b(yac[q][j] + Dh * xsv);
            }
        }
        if (tid < 64 && c + 1 < NCHUNKx) {
            float a = acb[(c + 1) * CHUNKx + tid];
            float a63 = __shfl(a, 63);
            float d = dtv[(size_t)(row0 + CHUNKx + tid) * NHEADSx + h];
            acss[tid] = a; eaS[tid] = __expf(a); dtS[tid] = d;
            ddS[tid] = d * __expf(a63 - a);
            if (tid == 0) dcS = __expf(a63);
        }
        __syncthreads();
        #pragma unroll
        for (int pt = 0; pt < 4; ++pt) {
            ushort4 pk;
            pk.x = f2b(sreg[pt][0]); pk.y = f2b(sreg[pt][1]);
            pk.z = f2b(sreg[pt][2]); pk.w = f2b(sreg[pt][3]);
            *(ushort4*)&Sp[(16 * pt + l15) * 136 + 16 * w + 4 * g] = pk;
        }
        if (c + 1 < NCHUNKx) {
            *(uint4*)&Bl[sr * 136 + scq * 8] = rB0;
            *(uint4*)&Bl[sr * 136 + 64 + scq * 8] = rB1;
            *(uint4*)&Cl[sr * 136 + scq * 8] = rC0;
            *(uint4*)&Cl[sr * 136 + 64 + scq * 8] = rC1;
            const u16* px = (const u16*)&rXs;
            const u16* pb0 = (const u16*)&rB0;
            const u16* pb1 = (const u16*)&rB1;
            float dd = ddS[sr];
            #pragma unroll
            for (int j = 0; j < 8; ++j) {
                Xt[(scq * 8 + j) * 72 + sgrp] = px[j];
                Bt[(scq * 8 + j) * 72 + sgrp] = f2b(b2f(pb0[j]) * dd);
                Bt[(64 + scq * 8 + j) * 72 + sgrp] = f2b(b2f(pb1[j]) * dd);
            }
        }
        __syncthreads();
    }
}

// ---------- gated RMSNorm in place over y ----------
__global__ __launch_bounds__(256) void rmsgate_k(u16* __restrict__ xb,
                                                 const u16* __restrict__ zb,
                                                 const float* __restrict__ w) {
    int row = blockIdx.x;
    const u16* zp = zb + (size_t)row * D_INNERx;
    u16* yp = xb + (size_t)row * LDX;
    float vals[8];
    float ss = 0.f;
    #pragma unroll
    for (int i = 0; i < 8; ++i) {
        int c = threadIdx.x + i * 256;
        float z = b2f(zp[c]);
        float y = b2f(yp[c]) * silu_f(z);
        vals[i] = y; ss += y * y;
    }
    float tot = block_sum(ss);
    float scale = rsqrtf(tot * (1.f / D_INNERx) + 1e-5f);
    #pragma unroll
    for (int i = 0; i < 8; ++i) {
        int c = threadIdx.x + i * 256;
        yp[c] = f2b(vals[i] * scale * w[c]);
    }
}

// ---------- hidden = out[:, -1, :] ----------
__global__ void hidden_k(float* __restrict__ out) {
    int i = blockIdx.x * blockDim.x + threadIdx.x;
    int b = i >> 10, d = i & 1023;
    out[(size_t)NTOK * D_MODELx + i] = out[((size_t)(b * LSEQ + LSEQ - 1)) * D_MODELx + d];
}

extern "C" void kernel_launch(void* const* d_in, const int* in_sizes, int n_in,
                              void* d_out, int out_size, void* d_ws, size_t ws_size,
                              hipStream_t stream) {
    const float* x       = (const float*)d_in[0];
    const float* Wi      = (const float*)d_in[1];
    const float* bi      = (const float*)d_in[2];
    const float* ln_g    = (const float*)d_in[3];
    const float* ln_b    = (const float*)d_in[4];
    const float* Win     = (const float*)d_in[5];
    const float* conv_w  = (const float*)d_in[6];
    const float* conv_b  = (const float*)d_in[7];
    const float* dt_bias = (const float*)d_in[8];
    const float* A_log   = (const float*)d_in[9];
    const float* Dv      = (const float*)d_in[10];
    const float* rms_w   = (const float*)d_in[11];
    const float* Wout    = (const float*)d_in[12];
    float* out = (float*)d_out;

    if (ws_size < 118489088ull) return;
    u16* xb  = (u16*)d_ws;                                   // [NTOK][LDX] bf16
    u16* ub  = xb + (size_t)NTOK * LDX;                      // [NTOK][1024] bf16
    u16* Woutb = ub;                                         // overlay after y ready
    u16* Rb  = ub + (size_t)NTOK * D_MODELx;                 // 8 MiB region
    u16* Wib  = Rb;                                          // 1024x1024
    u16* Winb = Rb + (size_t)1024 * 1024;                    // up to 2560x1024 (padded)
    float* acs = (float*)Rb;                                 // overlays Wib/Winb after GEMMs
    float* dtv = acs + (size_t)B_N * NHEADSx * NCHUNKx * CHUNKx;
    u16* xbf = xb;
    u16* zb  = (u16*)d_out;

    // 0. conversions
    cvt_f2b_k<<<16384, 256, 0, stream>>>(x, xbf, 16777216 / 4);
    cvt_f2b_k<<<1024, 256, 0, stream>>>(Wi, Wib, 1048576 / 4);
    // 1. u = x @ Wi^T + bi
    gemm_big<1><<<dim3(4, 64), 512, 0, stream>>>(
        xbf, Wib, bi, ub, NTOK, D_MODELx, D_INx, D_INx, D_MODELx);
    // 2. LayerNorm
    layernorm_k<<<NTOK, 256, 0, stream>>>(ub, ln_g, ln_b);
    // 3a. z = u @ Win[0:2048]^T -> d_out
    cvt_f2b_k<<<2048, 256, 0, stream>>>(Win, Winb, (2048 * 1024) / 4);
    gemm_big<1><<<dim3(8, 64), 512, 0, stream>>>(
        ub, Winb, nullptr, zb, NTOK, D_INNERx, D_MODELx, D_MODELx, D_INNERx);
    // 3b. xBCdt = u @ Win[2048:4384]^T -> xb  (N=2336 ragged; Winb padded to 2560 rows)
    cvt_f2b_k<<<2336, 256, 0, stream>>>(Win + (size_t)2048 * 1024, Winb, (2336 * 1024) / 4);
    gemm_big<1><<<dim3(10, 64), 512, 0, stream>>>(
        ub, Winb, nullptr, xb, NTOK, LDX, D_MODELx, D_MODELx, LDX);
    // 4. dt + per-chunk cumsum (wave-parallel scan)
    dt_acs_k<<<2048, 256, 0, stream>>>(xb, dt_bias, A_log, dtv, acs);
    // 5. conv + silu in place
    conv_k<<<dim3(CONV_DIMx / 32, B_N), 256, 0, stream>>>(xb, conv_w, conv_b);
    // 6+7. fused SSD v3
    ssd_k<<<dim3(NHEADSx, B_N), 512, 0, stream>>>(xb, dtv, acs, Dv);
    // 8. gated RMSNorm in place over y
    rmsgate_k<<<NTOK, 256, 0, stream>>>(xb, zb, rms_w);
    // 9. out = yn @ Wout^T
    cvt_f2b_k<<<2048, 256, 0, stream>>>(Wout, Woutb, (2048 * 1024) / 4);
    gemm_big<0><<<dim3(4, 64), 512, 0, stream>>>(
        xb, Woutb, nullptr, out, NTOK, D_MODELx, D_INNERx, LDX, D_MODELx);
    // 10. hidden
    hidden_k<<<(B_N * D_MODELx) / 256, 256, 0, stream>>>(out);
}

// Round 8
// 578.053 us; speedup vs baseline: 1.8907x; 1.0078x over previous
//
#include <hip/hip_runtime.h>
#include <math.h>

typedef unsigned short u16;
typedef __attribute__((ext_vector_type(8))) short bf16x8;
typedef __attribute__((ext_vector_type(4))) float f32x4;

#define B_N 8
#define LSEQ 2048
#define D_INx 1024
#define D_MODELx 1024
#define D_STATEx 128
#define D_INNERx 2048
#define NHEADSx 32
#define HEADDIMx 64
#define CONV_DIMx 2304
#define D_IN_PROJx 4384
#define CHUNKx 64
#define NCHUNKx 32
#define NTOK (B_N*LSEQ)   // 16384

#define LDX 2336
#define XB_B 2048
#define XB_C 2176
#define XB_DT 2304

// ---------- bf16 helpers (storage only; math fp32) ----------
__device__ __forceinline__ float b2f(u16 u) {
    return __uint_as_float(((unsigned)u) << 16);
}
__device__ __forceinline__ u16 f2b(float f) {
    unsigned u = __float_as_uint(f);
    return (u16)((u + 0x7FFFu + ((u >> 16) & 1u)) >> 16);  // RNE
}

__device__ __forceinline__ float block_sum(float v) {
    __shared__ float sm[8];
    int lane = threadIdx.x & 63, wid = threadIdx.x >> 6;
    #pragma unroll
    for (int o = 32; o; o >>= 1) v += __shfl_xor(v, o);
    __syncthreads();
    if (lane == 0) sm[wid] = v;
    __syncthreads();
    float r = 0.f;
    int nw = blockDim.x >> 6;
    for (int w = 0; w < nw; ++w) r += sm[w];
    return r;
}

__device__ __forceinline__ float silu_f(float x) {
    return x / (1.f + expf(-x));
}

// ---------- fp32 -> bf16 conversion ----------
__global__ __launch_bounds__(256) void cvt_f2b_k(const float* __restrict__ in,
                                                 u16* __restrict__ out, int n4) {
    int i = blockIdx.x * 256 + threadIdx.x;
    if (i >= n4) return;
    float4 v = ((const float4*)in)[i];
    ushort4 o;
    o.x = f2b(v.x); o.y = f2b(v.y); o.z = f2b(v.z); o.w = f2b(v.w);
    ((ushort4*)out)[i] = o;
}

// ---------- bf16 MFMA GEMM v3: 256x256, BK=64, 4-phase K-half schedule ----------
// C[M,N] = A[M,K] @ W[N,K]^T (+bias). M%256==0, K%64==0, nt=K/64 >= 4.
// LDS per buffer: [A0|B0|A1|B1], each half = [128 row-pairs][64 u16] with 8-slot
// XOR swizzle (slot = logical ^ (pair&7)); staging uses pre-swizzled per-lane
// GLOBAL source + linear LDS dest (rule #21). Per tile: two phases
// {read kk frags; lgkmcnt(0); barrier; stage next-tile same-half; MFMA x32},
// then one counted vmcnt(8) + barrier (never drain in loop).
template<int CBF>
__global__ __launch_bounds__(512) void gemm_big(const u16* __restrict__ A,
                                                const u16* __restrict__ W,
                                                const float* __restrict__ bias,
                                                void* __restrict__ Cv,
                                                int M, int N, int K, int lda, int ldc) {
    __shared__ u16 lds[65536];   // 2 buf x (A0 8192 | B0 8192 | A1 8192 | B1 8192)

    int nwgx = gridDim.x;
    int nwg = nwgx * gridDim.y;
    int bid = blockIdx.y * nwgx + blockIdx.x;
    int cpx = nwg >> 3;                        // grids here always %8==0
    bid = (bid & 7) * cpx + (bid >> 3);
    int bm = (bid / nwgx) * 256;
    int bn = (bid % nwgx) * 256;

    int tid = threadIdx.x, wid = tid >> 6, lane = tid & 63;
    int wm = wid >> 2, wn = wid & 3;           // 2 x 4 wave grid
    int lr = lane & 15, g = lane >> 4;

    // ---- staging source (per lane): line pr, slot s; logical = s ^ (pr&7) ----
    int prl = lane >> 3, slot = lane & 7;
    const u16 *sA0, *sA1, *sB0, *sB1;
    {
        int pr0 = wid * 16 + prl;
        int gl0 = slot ^ (pr0 & 7);
        int row0 = 2 * pr0 + (gl0 >> 2);
        int co0 = (gl0 & 3) << 3;
        sA0 = A + (size_t)(bm + row0) * lda + co0;
        sB0 = W + (size_t)(bn + row0) * (size_t)K + co0;
        int pr1 = wid * 16 + 8 + prl;
        int gl1 = slot ^ (pr1 & 7);
        int row1 = 2 * pr1 + (gl1 >> 2);
        int co1 = (gl1 & 3) << 3;
        sA1 = A + (size_t)(bm + row1) * lda + co1;
        sB1 = W + (size_t)(bn + row1) * (size_t)K + co1;
    }

    // ---- fragment read offsets (per lane, u16 units) ----
    int slt = (((lane & 1) << 2) | g) ^ ((lr >> 1) & 7);   // physical slot
    int laneA = (wm * 64 + (lr >> 1)) * 64 + (slt << 3);          // + m*512
    int laneB = 8192 + (wn * 32 + (lr >> 1)) * 64 + (slt << 3);   // + n*512

#define GL_(srcp, dstofs) __builtin_amdgcn_global_load_lds( \
        (const __attribute__((address_space(1))) void*)(srcp), \
        (__attribute__((address_space(3))) void*)(&lds[dstofs]), 16, 0, 0)

#define STAGE_HALF_(buf, kh, kt) { \
        size_t ko_ = (size_t)(kt) * 64 + (kh) * 32; \
        int rg_ = (buf) * 32768 + (kh) * 16384; \
        GL_(sA0 + ko_, rg_ + (wid * 16) * 64); \
        GL_(sB0 + ko_, rg_ + 8192 + (wid * 16) * 64); \
        GL_(sA1 + ko_, rg_ + (wid * 16 + 8) * 64); \
        GL_(sB1 + ko_, rg_ + 8192 + (wid * 16 + 8) * 64); \
    }

    f32x4 acc[8][4];
    #pragma unroll
    for (int m = 0; m < 8; ++m)
        #pragma unroll
        for (int n = 0; n < 4; ++n) acc[m][n] = (f32x4){0.f, 0.f, 0.f, 0.f};

    int nt = K >> 6;

    // prologue: stage tiles 0 and 1 fully (16 loads), wait tile 0 (8 remain)
    STAGE_HALF_(0, 0, 0); STAGE_HALF_(0, 1, 0);
    STAGE_HALF_(1, 0, 1); STAGE_HALF_(1, 1, 1);
    asm volatile("s_waitcnt vmcnt(8)" ::: "memory");
    __builtin_amdgcn_s_barrier();
    __builtin_amdgcn_sched_barrier(0);

    for (int t = 0; t < nt; ++t) {
        int bo = (t & 1) * 32768;
        bool more = (t + 2 < nt);

        #pragma unroll
        for (int kh = 0; kh < 2; ++kh) {
            int ho = bo + kh * 16384;
            bf16x8 af[8], bfr[4];
            #pragma unroll
            for (int n = 0; n < 4; ++n)
                bfr[n] = *(bf16x8*)&lds[ho + laneB + n * 512];
            #pragma unroll
            for (int m = 0; m < 8; ++m)
                af[m] = *(bf16x8*)&lds[ho + laneA + m * 512];
            asm volatile("s_waitcnt lgkmcnt(0)" ::: "memory");
            __builtin_amdgcn_sched_barrier(0);
            __builtin_amdgcn_s_barrier();       // all waves' kh reads done
            __builtin_amdgcn_sched_barrier(0);
            if (more) STAGE_HALF_((t & 1), kh, t + 2);   // overwrite dead half
            __builtin_amdgcn_s_setprio(1);
            #pragma unroll
            for (int m = 0; m < 8; ++m)
                #pragma unroll
                for (int n = 0; n < 4; ++n)
                    acc[m][n] = __builtin_amdgcn_mfma_f32_16x16x32_bf16(af[m], bfr[n], acc[m][n], 0, 0, 0);
            __builtin_amdgcn_s_setprio(0);
        }

        if (t + 1 < nt) {
            if (more) { asm volatile("s_waitcnt vmcnt(8)" ::: "memory"); }
            else      { asm volatile("s_waitcnt vmcnt(0)" ::: "memory"); }
            __builtin_amdgcn_s_barrier();       // next tile landed for all
            __builtin_amdgcn_sched_barrier(0);
        }
    }
#undef STAGE_HALF_
#undef GL_

    // epilogue: C-write (predicated on col < N)
    int crow = bm + wm * 128 + (g << 2);
    int ccol = bn + wn * 64 + lr;
    #pragma unroll
    for (int n = 0; n < 4; ++n) {
        int col = ccol + n * 16;
        if (col < N) {
            float bv = bias ? bias[col] : 0.f;
            #pragma unroll
            for (int m = 0; m < 8; ++m) {
                #pragma unroll
                for (int j = 0; j < 4; ++j) {
                    int row = crow + m * 16 + j;
                    float v = acc[m][n][j] + bv;
                    if constexpr (CBF) ((u16*)Cv)[(size_t)row * ldc + col] = f2b(v);
                    else               ((float*)Cv)[(size_t)row * ldc + col] = v;
                }
            }
        }
    }
}

// ---------- LayerNorm (in place on bf16 u) ----------
__global__ __launch_bounds__(256) void layernorm_k(u16* __restrict__ u,
                                                   const float* __restrict__ g,
                                                   const float* __restrict__ bt) {
    int row = blockIdx.x;
    u16* p = u + (size_t)row * D_MODELx;
    float v[4]; float s = 0.f;
    #pragma unroll
    for (int i = 0; i < 4; ++i) { v[i] = b2f(p[threadIdx.x + i * 256]); s += v[i]; }
    float mean = block_sum(s) * (1.f / D_MODELx);
    float vs = 0.f;
    #pragma unroll
    for (int i = 0; i < 4; ++i) { float d = v[i] - mean; vs += d * d; }
    float var = block_sum(vs) * (1.f / D_MODELx);
    float inv = rsqrtf(var + 1e-5f);
    #pragma unroll
    for (int i = 0; i < 4; ++i) {
        int c = threadIdx.x + i * 256;
        p[c] = f2b((v[i] - mean) * inv * g[c] + bt[c]);
    }
}

// ---------- dt softplus + per-chunk cumsum: one wave per (b,h,c) ----------
__global__ __launch_bounds__(256) void dt_acs_k(const u16* __restrict__ xb,
                                                const float* __restrict__ dt_bias,
                                                const float* __restrict__ A_log,
                                                float* __restrict__ dtv, float* __restrict__ acs) {
    int gid = blockIdx.x * 4 + (threadIdx.x >> 6);
    int lane = threadIdx.x & 63;
    int c = gid & 31;
    int h = (gid >> 5) & 31;
    int b = gid >> 10;
    float A = -expf(A_log[h]);
    int row = b * LSEQ + c * CHUNKx + lane;
    float x = b2f(xb[(size_t)row * LDX + XB_DT + h]) + dt_bias[h];
    float d = (x > 20.f) ? x : log1pf(expf(x));
    dtv[(size_t)row * NHEADSx + h] = d;
    float v = A * d;
    #pragma unroll
    for (int off = 1; off < 64; off <<= 1) {
        float t = __shfl_up(v, off);
        if (lane >= off) v += t;
    }
    acs[(((size_t)(b * NHEADSx + h)) * NCHUNKx + c) * CHUNKx + lane] = v;
}

// ---------- causal depthwise conv (k=4) + SiLU, in place ----------
__global__ __launch_bounds__(256) void conv_k(u16* __restrict__ xb,
                                              const float* __restrict__ w,
                                              const float* __restrict__ bias) {
    int chl = threadIdx.x & 31, seg = threadIdx.x >> 5;
    int ch = blockIdx.x * 32 + chl;
    int b = blockIdx.y;
    float w0 = w[ch * 4 + 0], w1 = w[ch * 4 + 1], w2 = w[ch * 4 + 2], w3 = w[ch * 4 + 3];
    float bs = bias[ch];
    size_t base = ((size_t)b * LSEQ + seg * 256) * LDX + ch;
    float h0 = 0.f, h1 = 0.f, h2 = 0.f;
    if (seg) {
        h0 = b2f(xb[base - 3 * (size_t)LDX]);
        h1 = b2f(xb[base - 2 * (size_t)LDX]);
        h2 = b2f(xb[base - 1 * (size_t)LDX]);
    }
    __syncthreads();
    for (int i = 0; i < 256; ++i) {
        float xl = b2f(xb[base + (size_t)i * LDX]);
        float o = fmaf(w3, xl, fmaf(w2, h2, fmaf(w1, h1, fmaf(w0, h0, bs))));
        xb[base + (size_t)i * LDX] = f2b(silu_f(o));
        h0 = h1; h1 = h2; h2 = xl;
    }
}

// ---------- fused SSD v3 (verified round 6) ----------
__global__ __launch_bounds__(512) void ssd_k(u16* __restrict__ xb,
                                             const float* __restrict__ dtv,
                                             const float* __restrict__ acs,
                                             const float* __restrict__ Dp) {
    __shared__ u16 Xt[64 * 72];
    __shared__ u16 Bl[64 * 136];
    __shared__ u16 Bt[128 * 72];
    __shared__ u16 Cl[64 * 136];
    __shared__ u16 Gp[64 * 72];
    __shared__ u16 Sp[64 * 136];
    __shared__ float acss[64], eaS[64], dtS[64], ddS[64];
    __shared__ float dcS;

    int h = blockIdx.x, b = blockIdx.y;
    int tid = threadIdx.x;
    int w = tid >> 6, lane = tid & 63, l15 = lane & 15, g = lane >> 4;
    int lt = w >> 1, hf = w & 1;
    float Dh = Dp[h];

    int sr = tid >> 3, scq = tid & 7;
    int srh = sr >> 3, srl = sr & 7;
    int sgrp = ((srh ^ scq) << 3) + srl;

    f32x4 sreg[4];
    #pragma unroll
    for (int pt = 0; pt < 4; ++pt) sreg[pt] = (f32x4){0.f, 0.f, 0.f, 0.f};

    const float* acb = acs + ((size_t)(b * NHEADSx + h)) * NCHUNKx * CHUNKx;

    for (int i = tid; i < 64 * 136 / 8; i += 512) ((uint4*)Sp)[i] = (uint4){0, 0, 0, 0};

    if (tid < 64) {
        float a = acb[tid];
        float a63 = __shfl(a, 63);
        float d = dtv[(size_t)(b * LSEQ + tid) * NHEADSx + h];
        acss[tid] = a; eaS[tid] = __expf(a); dtS[tid] = d;
        ddS[tid] = d * __expf(a63 - a);
        if (tid == 0) dcS = __expf(a63);
    }
    uint4 rXs, rB0, rB1, rC0, rC1;
    {
        size_t rowb = ((size_t)(b * LSEQ) + sr) * LDX;
        rXs = *(const uint4*)(xb + rowb + h * 64 + scq * 8);
        rB0 = *(const uint4*)(xb + rowb + XB_B + scq * 8);
        rB1 = *(const uint4*)(xb + rowb + XB_B + 64 + scq * 8);
        rC0 = *(const uint4*)(xb + rowb + XB_C + scq * 8);
        rC1 = *(const uint4*)(xb + rowb + XB_C + 64 + scq * 8);
    }
    __syncthreads();
    {
        *(uint4*)&Bl[sr * 136 + scq * 8] = rB0;
        *(uint4*)&Bl[sr * 136 + 64 + scq * 8] = rB1;
        *(uint4*)&Cl[sr * 136 + scq * 8] = rC0;
        *(uint4*)&Cl[sr * 136 + 64 + scq * 8] = rC1;
        const u16* px = (const u16*)&rXs;
        const u16* pb0 = (const u16*)&rB0;
        const u16* pb1 = (const u16*)&rB1;
        float dd = ddS[sr];
        #pragma unroll
        for (int j = 0; j < 8; ++j) {
            Xt[(scq * 8 + j) * 72 + sgrp] = px[j];
            Bt[(scq * 8 + j) * 72 + sgrp] = f2b(b2f(pb0[j]) * dd);
            Bt[(64 + scq * 8 + j) * 72 + sgrp] = f2b(b2f(pb1[j]) * dd);
        }
    }
    __syncthreads();

    for (int c = 0; c < NCHUNKx; ++c) {
        int row0 = b * LSEQ + c * CHUNKx;
        if (c + 1 < NCHUNKx) {
            size_t rowb = ((size_t)row0 + CHUNKx + sr) * LDX;
            rXs = *(const uint4*)(xb + rowb + h * 64 + scq * 8);
            rB0 = *(const uint4*)(xb + rowb + XB_B + scq * 8);
            rB1 = *(const uint4*)(xb + rowb + XB_B + 64 + scq * 8);
            rC0 = *(const uint4*)(xb + rowb + XB_C + scq * 8);
            rC1 = *(const uint4*)(xb + rowb + XB_C + 64 + scq * 8);
        }
        f32x4 accG[2], yac[2];
        accG[0] = (f32x4){0.f, 0.f, 0.f, 0.f}; accG[1] = (f32x4){0.f, 0.f, 0.f, 0.f};
        yac[0] = (f32x4){0.f, 0.f, 0.f, 0.f};  yac[1] = (f32x4){0.f, 0.f, 0.f, 0.f};
        #pragma unroll
        for (int kk = 0; kk < 4; ++kk) {
            bf16x8 aC = *(bf16x8*)&Cl[(16 * lt + l15) * 136 + 32 * kk + 8 * g];
            #pragma unroll
            for (int q = 0; q < 2; ++q) {
                int st = 16 * (2 * hf + q) + l15;
                bf16x8 bB = *(bf16x8*)&Bl[st * 136 + 32 * kk + 8 * g];
                accG[q] = __builtin_amdgcn_mfma_f32_16x16x32_bf16(aC, bB, accG[q], 0, 0, 0);
                bf16x8 bS = *(bf16x8*)&Sp[st * 136 + 32 * kk + 8 * g];
                yac[q] = __builtin_amdgcn_mfma_f32_16x16x32_bf16(aC, bS, yac[q], 0, 0, 0);
            }
        }
        float dc = dcS;
        #pragma unroll
        for (int q = 0; q < 2; ++q) {
            int s = 16 * (2 * hf + q) + l15;
            float as = acss[s], ds = dtS[s];
            #pragma unroll
            for (int j = 0; j < 4; ++j) {
                int l = 16 * lt + 4 * g + j;
                yac[q][j] *= eaS[l];
                float v = (s <= l) ? accG[q][j] * __expf(acss[l] - as) * ds : 0.f;
                Gp[l * 72 + s] = f2b(v);
            }
        }
        #pragma unroll
        for (int pt = 0; pt < 4; ++pt)
            #pragma unroll
            for (int j = 0; j < 4; ++j) sreg[pt][j] *= dc;
        __syncthreads();

        #pragma unroll
        for (int kk = 0; kk < 2; ++kk) {
            bf16x8 aG = *(bf16x8*)&Gp[(16 * lt + l15) * 72 + 32 * kk + 8 * g];
            #pragma unroll
            for (int q = 0; q < 2; ++q) {
                int row = 16 * (2 * hf + q) + l15;
                int grp = (4 * kk + g) ^ ((row >> 3) & 7);
                bf16x8 bXq = *(bf16x8*)&Xt[row * 72 + grp * 8];
                yac[q] = __builtin_amdgcn_mfma_f32_16x16x32_bf16(aG, bXq, yac[q], 0, 0, 0);
            }
            int rowb = 16 * w + l15;
            int grpb = (4 * kk + g) ^ ((rowb >> 3) & 7);
            bf16x8 aB = *(bf16x8*)&Bt[rowb * 72 + grpb * 8];
            #pragma unroll
            for (int pt = 0; pt < 4; ++pt) {
                int row = 16 * pt + l15;
                int grp = (4 * kk + g) ^ ((row >> 3) & 7);
                bf16x8 bX = *(bf16x8*)&Xt[row * 72 + grp * 8];
                sreg[pt] = __builtin_amdgcn_mfma_f32_16x16x32_bf16(aB, bX, sreg[pt], 0, 0, 0);
            }
        }
        #pragma unroll
        for (int q = 0; q < 2; ++q) {
            int p = 16 * (2 * hf + q) + l15;
            int ph = (p >> 3) & 7;
            #pragma unroll
            for (int j = 0; j < 4; ++j) {
                int l = 16 * lt + 4 * g + j;
                int col = (((l >> 3) ^ ph) << 3) + (l & 7);
                float xsv = b2f(Xt[p * 72 + col]);
                xb[(size_t)(row0 + l) * LDX + h * 64 + p] = f2b(yac[q][j] + Dh * xsv);
            }
        }
        if (tid < 64 && c + 1 < NCHUNKx) {
            float a = acb[(c + 1) * CHUNKx + tid];
            float a63 = __shfl(a, 63);
            float d = dtv[(size_t)(row0 + CHUNKx + tid) * NHEADSx + h];
            acss[tid] = a; eaS[tid] = __expf(a); dtS[tid] = d;
            ddS[tid] = d * __expf(a63 - a);
            if (tid == 0) dcS = __expf(a63);
        }
        __syncthreads();
        #pragma unroll
        for (int pt = 0; pt < 4; ++pt) {
            ushort4 pk;
            pk.x = f2b(sreg[pt][0]); pk.y = f2b(sreg[pt][1]);
            pk.z = f2b(sreg[pt][2]); pk.w = f2b(sreg[pt][3]);
            *(ushort4*)&Sp[(16 * pt + l15) * 136 + 16 * w + 4 * g] = pk;
        }
        if (c + 1 < NCHUNKx) {
            *(uint4*)&Bl[sr * 136 + scq * 8] = rB0;
            *(uint4*)&Bl[sr * 136 + 64 + scq * 8] = rB1;
            *(uint4*)&Cl[sr * 136 + scq * 8] = rC0;
            *(uint4*)&Cl[sr * 136 + 64 + scq * 8] = rC1;
            const u16* px = (const u16*)&rXs;
            const u16* pb0 = (const u16*)&rB0;
            const u16* pb1 = (const u16*)&rB1;
            float dd = ddS[sr];
            #pragma unroll
            for (int j = 0; j < 8; ++j) {
                Xt[(scq * 8 + j) * 72 + sgrp] = px[j];
                Bt[(scq * 8 + j) * 72 + sgrp] = f2b(b2f(pb0[j]) * dd);
                Bt[(64 + scq * 8 + j) * 72 + sgrp] = f2b(b2f(pb1[j]) * dd);
            }
        }
        __syncthreads();
    }
}

// ---------- gated RMSNorm in place over y ----------
__global__ __launch_bounds__(256) void rmsgate_k(u16* __restrict__ xb,
                                                 const u16* __restrict__ zb,
                                                 const float* __restrict__ w) {
    int row = blockIdx.x;
    const u16* zp = zb + (size_t)row * D_INNERx;
    u16* yp = xb + (size_t)row * LDX;
    float vals[8];
    float ss = 0.f;
    #pragma unroll
    for (int i = 0; i < 8; ++i) {
        int c = threadIdx.x + i * 256;
        float z = b2f(zp[c]);
        float y = b2f(yp[c]) * silu_f(z);
        vals[i] = y; ss += y * y;
    }
    float tot = block_sum(ss);
    float scale = rsqrtf(tot * (1.f / D_INNERx) + 1e-5f);
    #pragma unroll
    for (int i = 0; i < 8; ++i) {
        int c = threadIdx.x + i * 256;
        yp[c] = f2b(vals[i] * scale * w[c]);
    }
}

// ---------- hidden = out[:, -1, :] ----------
__global__ void hidden_k(float* __restrict__ out) {
    int i = blockIdx.x * blockDim.x + threadIdx.x;
    int b = i >> 10, d = i & 1023;
    out[(size_t)NTOK * D_MODELx + i] = out[((size_t)(b * LSEQ + LSEQ - 1)) * D_MODELx + d];
}

extern "C" void kernel_launch(void* const* d_in, const int* in_sizes, int n_in,
                              void* d_out, int out_size, void* d_ws, size_t ws_size,
                              hipStream_t stream) {
    const float* x       = (const float*)d_in[0];
    const float* Wi      = (const float*)d_in[1];
    const float* bi      = (const float*)d_in[2];
    const float* ln_g    = (const float*)d_in[3];
    const float* ln_b    = (const float*)d_in[4];
    const float* Win     = (const float*)d_in[5];
    const float* conv_w  = (const float*)d_in[6];
    const float* conv_b  = (const float*)d_in[7];
    const float* dt_bias = (const float*)d_in[8];
    const float* A_log   = (const float*)d_in[9];
    const float* Dv      = (const float*)d_in[10];
    const float* rms_w   = (const float*)d_in[11];
    const float* Wout    = (const float*)d_in[12];
    float* out = (float*)d_out;

    if (ws_size < 118489088ull) return;
    u16* xb  = (u16*)d_ws;                                   // [NTOK][LDX] bf16
    u16* ub  = xb + (size_t)NTOK * LDX;                      // [NTOK][1024] bf16
    u16* Woutb = ub;                                         // overlay after y ready
    u16* Rb  = ub + (size_t)NTOK * D_MODELx;                 // 8 MiB region
    u16* Wib  = Rb;                                          // 1024x1024
    u16* Winb = Rb + (size_t)1024 * 1024;                    // up to 2560x1024 (padded)
    float* acs = (float*)Rb;                                 // overlays Wib/Winb after GEMMs
    float* dtv = acs + (size_t)B_N * NHEADSx * NCHUNKx * CHUNKx;
    u16* xbf = xb;
    u16* zb  = (u16*)d_out;

    // 0. conversions
    cvt_f2b_k<<<16384, 256, 0, stream>>>(x, xbf, 16777216 / 4);
    cvt_f2b_k<<<1024, 256, 0, stream>>>(Wi, Wib, 1048576 / 4);
    // 1. u = x @ Wi^T + bi
    gemm_big<1><<<dim3(4, 64), 512, 0, stream>>>(
        xbf, Wib, bi, ub, NTOK, D_MODELx, D_INx, D_INx, D_MODELx);
    // 2. LayerNorm
    layernorm_k<<<NTOK, 256, 0, stream>>>(ub, ln_g, ln_b);
    // 3a. z = u @ Win[0:2048]^T -> d_out
    cvt_f2b_k<<<2048, 256, 0, stream>>>(Win, Winb, (2048 * 1024) / 4);
    gemm_big<1><<<dim3(8, 64), 512, 0, stream>>>(
        ub, Winb, nullptr, zb, NTOK, D_INNERx, D_MODELx, D_MODELx, D_INNERx);
    // 3b. xBCdt = u @ Win[2048:4384]^T -> xb  (N=2336 ragged; Winb padded to 2560 rows)
    cvt_f2b_k<<<2336, 256, 0, stream>>>(Win + (size_t)2048 * 1024, Winb, (2336 * 1024) / 4);
    gemm_big<1><<<dim3(10, 64), 512, 0, stream>>>(
        ub, Winb, nullptr, xb, NTOK, LDX, D_MODELx, D_MODELx, LDX);
    // 4. dt + per-chunk cumsum (wave-parallel scan)
    dt_acs_k<<<2048, 256, 0, stream>>>(xb, dt_bias, A_log, dtv, acs);
    // 5. conv + silu in place
    conv_k<<<dim3(CONV_DIMx / 32, B_N), 256, 0, stream>>>(xb, conv_w, conv_b);
    // 6+7. fused SSD v3
    ssd_k<<<dim3(NHEADSx, B_N), 512, 0, stream>>>(xb, dtv, acs, Dv);
    // 8. gated RMSNorm in place over y
    rmsgate_k<<<NTOK, 256, 0, stream>>>(xb, zb, rms_w);
    // 9. out = yn @ Wout^T
    cvt_f2b_k<<<2048, 256, 0, stream>>>(Wout, Woutb, (2048 * 1024) / 4);
    gemm_big<0><<<dim3(4, 64), 512, 0, stream>>>(
        xb, Woutb, nullptr, out, NTOK, D_MODELx, D_INNERx, LDX, D_MODELx);
    // 10. hidden
    hidden_k<<<(B_N * D_MODELx) / 256, 256, 0, stream>>>(out);
}

// Round 9
// 573.202 us; speedup vs baseline: 1.9067x; 1.0085x over previous
//
#include <hip/hip_runtime.h>
#include <math.h>

typedef unsigned short u16;
typedef __attribute__((ext_vector_type(8))) short bf16x8;
typedef __attribute__((ext_vector_type(4))) float f32x4;

#define B_N 8
#define LSEQ 2048
#define D_INx 1024
#define D_MODELx 1024
#define D_STATEx 128
#define D_INNERx 2048
#define NHEADSx 32
#define HEADDIMx 64
#define CONV_DIMx 2304
#define D_IN_PROJx 4384
#define CHUNKx 64
#define NCHUNKx 32
#define NTOK (B_N*LSEQ)   // 16384

#define LDX 2336
#define XB_B 2048
#define XB_C 2176
#define XB_DT 2304

// ---------- bf16 helpers (storage only; math fp32) ----------
__device__ __forceinline__ float b2f(u16 u) {
    return __uint_as_float(((unsigned)u) << 16);
}
__device__ __forceinline__ u16 f2b(float f) {
    unsigned u = __float_as_uint(f);
    return (u16)((u + 0x7FFFu + ((u >> 16) & 1u)) >> 16);  // RNE
}

__device__ __forceinline__ float block_sum(float v) {
    __shared__ float sm[8];
    int lane = threadIdx.x & 63, wid = threadIdx.x >> 6;
    #pragma unroll
    for (int o = 32; o; o >>= 1) v += __shfl_xor(v, o);
    __syncthreads();
    if (lane == 0) sm[wid] = v;
    __syncthreads();
    float r = 0.f;
    int nw = blockDim.x >> 6;
    for (int w = 0; w < nw; ++w) r += sm[w];
    return r;
}

__device__ __forceinline__ float silu_f(float x) {
    return x / (1.f + expf(-x));
}

// ---------- fp32 -> bf16 conversion ----------
__global__ __launch_bounds__(256) void cvt_f2b_k(const float* __restrict__ in,
                                                 u16* __restrict__ out, int n4) {
    int i = blockIdx.x * 256 + threadIdx.x;
    if (i >= n4) return;
    float4 v = ((const float4*)in)[i];
    ushort4 o;
    o.x = f2b(v.x); o.y = f2b(v.y); o.z = f2b(v.z); o.w = f2b(v.w);
    ((ushort4*)out)[i] = o;
}

// ---------- bf16 MFMA GEMM v4: 256x256, ring of 4 K-half slots, m201-style waits ----------
// C[M,N] = A[M,K] @ W[N,K]^T (+bias). M%256==0, K%64==0 (nt>=2).
// Phase q (q=0..2*nt-1) consumes slot q&3 (16K u16 = A-half 8192 | B-half 8192).
// Per phase: {ds_reads(slot q) | stage(phase q+3 -> slot (q+3)&3); barrier;
// lgkmcnt(0); MFMA x32; counted vmcnt(8/4/0); barrier}. vmcnt for slot q+1's
// data retires 3 phases after its stage was issued -> full latency cover.
template<int CBF>
__global__ __launch_bounds__(512) void gemm_big(const u16* __restrict__ A,
                                                const u16* __restrict__ W,
                                                const float* __restrict__ bias,
                                                void* __restrict__ Cv,
                                                int M, int N, int K, int lda, int ldc) {
    __shared__ u16 lds[65536];   // 4 slots x 16384 u16

    int nwgx = gridDim.x;
    int nwg = nwgx * gridDim.y;
    int bid = blockIdx.y * nwgx + blockIdx.x;
    int cpx = nwg >> 3;                        // grids here always %8==0
    bid = (bid & 7) * cpx + (bid >> 3);
    int bm = (bid / nwgx) * 256;
    int bn = (bid % nwgx) * 256;

    int tid = threadIdx.x, wid = tid >> 6, lane = tid & 63;
    int wm = wid >> 2, wn = wid & 3;           // 2 x 4 wave grid
    int lr = lane & 15, g = lane >> 4;

    // ---- staging source (per lane): line pr, slot s; logical = s ^ (pr&7) ----
    int prl = lane >> 3, slot = lane & 7;
    const u16 *sA0, *sA1, *sB0, *sB1;
    {
        int pr0 = wid * 16 + prl;
        int gl0 = slot ^ (pr0 & 7);
        int row0 = 2 * pr0 + (gl0 >> 2);
        int co0 = (gl0 & 3) << 3;
        sA0 = A + (size_t)(bm + row0) * lda + co0;
        sB0 = W + (size_t)(bn + row0) * (size_t)K + co0;
        int pr1 = wid * 16 + 8 + prl;
        int gl1 = slot ^ (pr1 & 7);
        int row1 = 2 * pr1 + (gl1 >> 2);
        int co1 = (gl1 & 3) << 3;
        sA1 = A + (size_t)(bm + row1) * lda + co1;
        sB1 = W + (size_t)(bn + row1) * (size_t)K + co1;
    }

    // ---- fragment read offsets (per lane, u16 units) ----
    int slt = (((lane & 1) << 2) | g) ^ ((lr >> 1) & 7);   // physical slot-of-8
    int laneA = (wm * 64 + (lr >> 1)) * 64 + (slt << 3);          // + m*512
    int laneB = 8192 + (wn * 32 + (lr >> 1)) * 64 + (slt << 3);   // + n*512

#define GL_(srcp, dstofs) __builtin_amdgcn_global_load_lds( \
        (const __attribute__((address_space(1))) void*)(srcp), \
        (__attribute__((address_space(3))) void*)(&lds[dstofs]), 16, 0, 0)

    // stage data for global phase p into slot p&3 (4 loads/wave)
#define STAGE_(p) { \
        size_t ko_ = (size_t)((p) >> 1) * 64 + ((p) & 1) * 32; \
        int rg_ = ((p) & 3) * 16384; \
        GL_(sA0 + ko_, rg_ + (wid * 16) * 64); \
        GL_(sB0 + ko_, rg_ + 8192 + (wid * 16) * 64); \
        GL_(sA1 + ko_, rg_ + (wid * 16 + 8) * 64); \
        GL_(sB1 + ko_, rg_ + 8192 + (wid * 16 + 8) * 64); \
    }

    f32x4 acc[8][4];
    #pragma unroll
    for (int m = 0; m < 8; ++m)
        #pragma unroll
        for (int n = 0; n < 4; ++n) acc[m][n] = (f32x4){0.f, 0.f, 0.f, 0.f};

    int nph = K >> 5;   // 2*nt phases

    // prologue: stage phases 0,1,2; wait phase-0 data (groups 1,2 outstanding)
    STAGE_(0); STAGE_(1); STAGE_(2);
    asm volatile("s_waitcnt vmcnt(8)" ::: "memory");
    __builtin_amdgcn_s_barrier();
    __builtin_amdgcn_sched_barrier(0);

    for (int q = 0; q < nph; ++q) {
        int ho = (q & 3) * 16384;
        // issue this phase's fragment reads (waited after the barrier)
        bf16x8 af[8], bfr[4];
        #pragma unroll
        for (int n = 0; n < 4; ++n)
            bfr[n] = *(bf16x8*)&lds[ho + laneB + n * 512];
        #pragma unroll
        for (int m = 0; m < 8; ++m)
            af[m] = *(bf16x8*)&lds[ho + laneA + m * 512];
        // prefetch 3 phases ahead into the slot freed by phase q-1
        if (q + 3 < nph) STAGE_(q + 3);
        __builtin_amdgcn_sched_barrier(0);
        __builtin_amdgcn_s_barrier();
        asm volatile("s_waitcnt lgkmcnt(0)" ::: "memory");
        __builtin_amdgcn_sched_barrier(0);
        __builtin_amdgcn_s_setprio(1);
        #pragma unroll
        for (int m = 0; m < 8; ++m)
            #pragma unroll
            for (int n = 0; n < 4; ++n)
                acc[m][n] = __builtin_amdgcn_mfma_f32_16x16x32_bf16(af[m], bfr[n], acc[m][n], 0, 0, 0);
        __builtin_amdgcn_s_setprio(0);
        __builtin_amdgcn_sched_barrier(0);
        if (q + 1 < nph) {
            // ensure slot (q+1)&3's data (staged at q-2) retired; keep newer in flight
            if (q + 4 <= nph)      { asm volatile("s_waitcnt vmcnt(8)" ::: "memory"); }
            else if (q + 3 == nph) { asm volatile("s_waitcnt vmcnt(4)" ::: "memory"); }
            else                   { asm volatile("s_waitcnt vmcnt(0)" ::: "memory"); }
            __builtin_amdgcn_s_barrier();
            __builtin_amdgcn_sched_barrier(0);
        }
    }
#undef STAGE_
#undef GL_

    // epilogue: C-write (predicated on col < N)
    int crow = bm + wm * 128 + (g << 2);
    int ccol = bn + wn * 64 + lr;
    #pragma unroll
    for (int n = 0; n < 4; ++n) {
        int col = ccol + n * 16;
        if (col < N) {
            float bv = bias ? bias[col] : 0.f;
            #pragma unroll
            for (int m = 0; m < 8; ++m) {
                #pragma unroll
                for (int j = 0; j < 4; ++j) {
                    int row = crow + m * 16 + j;
                    float v = acc[m][n][j] + bv;
                    if constexpr (CBF) ((u16*)Cv)[(size_t)row * ldc + col] = f2b(v);
                    else               ((float*)Cv)[(size_t)row * ldc + col] = v;
                }
            }
        }
    }
}

// ---------- LayerNorm (in place on bf16 u) ----------
__global__ __launch_bounds__(256) void layernorm_k(u16* __restrict__ u,
                                                   const float* __restrict__ g,
                                                   const float* __restrict__ bt) {
    int row = blockIdx.x;
    u16* p = u + (size_t)row * D_MODELx;
    float v[4]; float s = 0.f;
    #pragma unroll
    for (int i = 0; i < 4; ++i) { v[i] = b2f(p[threadIdx.x + i * 256]); s += v[i]; }
    float mean = block_sum(s) * (1.f / D_MODELx);
    float vs = 0.f;
    #pragma unroll
    for (int i = 0; i < 4; ++i) { float d = v[i] - mean; vs += d * d; }
    float var = block_sum(vs) * (1.f / D_MODELx);
    float inv = rsqrtf(var + 1e-5f);
    #pragma unroll
    for (int i = 0; i < 4; ++i) {
        int c = threadIdx.x + i * 256;
        p[c] = f2b((v[i] - mean) * inv * g[c] + bt[c]);
    }
}

// ---------- dt softplus + per-chunk cumsum: one wave per (b,h,c) ----------
__global__ __launch_bounds__(256) void dt_acs_k(const u16* __restrict__ xb,
                                                const float* __restrict__ dt_bias,
                                                const float* __restrict__ A_log,
                                                float* __restrict__ dtv, float* __restrict__ acs) {
    int gid = blockIdx.x * 4 + (threadIdx.x >> 6);
    int lane = threadIdx.x & 63;
    int c = gid & 31;
    int h = (gid >> 5) & 31;
    int b = gid >> 10;
    float A = -expf(A_log[h]);
    int row = b * LSEQ + c * CHUNKx + lane;
    float x = b2f(xb[(size_t)row * LDX + XB_DT + h]) + dt_bias[h];
    float d = (x > 20.f) ? x : log1pf(expf(x));
    dtv[(size_t)row * NHEADSx + h] = d;
    float v = A * d;
    #pragma unroll
    for (int off = 1; off < 64; off <<= 1) {
        float t = __shfl_up(v, off);
        if (lane >= off) v += t;
    }
    acs[(((size_t)(b * NHEADSx + h)) * NCHUNKx + c) * CHUNKx + lane] = v;
}

// ---------- causal depthwise conv (k=4) + SiLU, in place ----------
__global__ __launch_bounds__(256) void conv_k(u16* __restrict__ xb,
                                              const float* __restrict__ w,
                                              const float* __restrict__ bias) {
    int chl = threadIdx.x & 31, seg = threadIdx.x >> 5;
    int ch = blockIdx.x * 32 + chl;
    int b = blockIdx.y;
    float w0 = w[ch * 4 + 0], w1 = w[ch * 4 + 1], w2 = w[ch * 4 + 2], w3 = w[ch * 4 + 3];
    float bs = bias[ch];
    size_t base = ((size_t)b * LSEQ + seg * 256) * LDX + ch;
    float h0 = 0.f, h1 = 0.f, h2 = 0.f;
    if (seg) {
        h0 = b2f(xb[base - 3 * (size_t)LDX]);
        h1 = b2f(xb[base - 2 * (size_t)LDX]);
        h2 = b2f(xb[base - 1 * (size_t)LDX]);
    }
    __syncthreads();
    for (int i = 0; i < 256; ++i) {
        float xl = b2f(xb[base + (size_t)i * LDX]);
        float o = fmaf(w3, xl, fmaf(w2, h2, fmaf(w1, h1, fmaf(w0, h0, bs))));
        xb[base + (size_t)i * LDX] = f2b(silu_f(o));
        h0 = h1; h1 = h2; h2 = xl;
    }
}

// ---------- fused SSD v3 (verified round 6) ----------
__global__ __launch_bounds__(512) void ssd_k(u16* __restrict__ xb,
                                             const float* __restrict__ dtv,
                                             const float* __restrict__ acs,
                                             const float* __restrict__ Dp) {
    __shared__ u16 Xt[64 * 72];
    __shared__ u16 Bl[64 * 136];
    __shared__ u16 Bt[128 * 72];
    __shared__ u16 Cl[64 * 136];
    __shared__ u16 Gp[64 * 72];
    __shared__ u16 Sp[64 * 136];
    __shared__ float acss[64], eaS[64], dtS[64], ddS[64];
    __shared__ float dcS;

    int h = blockIdx.x, b = blockIdx.y;
    int tid = threadIdx.x;
    int w = tid >> 6, lane = tid & 63, l15 = lane & 15, g = lane >> 4;
    int lt = w >> 1, hf = w & 1;
    float Dh = Dp[h];

    int sr = tid >> 3, scq = tid & 7;
    int srh = sr >> 3, srl = sr & 7;
    int sgrp = ((srh ^ scq) << 3) + srl;

    f32x4 sreg[4];
    #pragma unroll
    for (int pt = 0; pt < 4; ++pt) sreg[pt] = (f32x4){0.f, 0.f, 0.f, 0.f};

    const float* acb = acs + ((size_t)(b * NHEADSx + h)) * NCHUNKx * CHUNKx;

    for (int i = tid; i < 64 * 136 / 8; i += 512) ((uint4*)Sp)[i] = (uint4){0, 0, 0, 0};

    if (tid < 64) {
        float a = acb[tid];
        float a63 = __shfl(a, 63);
        float d = dtv[(size_t)(b * LSEQ + tid) * NHEADSx + h];
        acss[tid] = a; eaS[tid] = __expf(a); dtS[tid] = d;
        ddS[tid] = d * __expf(a63 - a);
        if (tid == 0) dcS = __expf(a63);
    }
    uint4 rXs, rB0, rB1, rC0, rC1;
    {
        size_t rowb = ((size_t)(b * LSEQ) + sr) * LDX;
        rXs = *(const uint4*)(xb + rowb + h * 64 + scq * 8);
        rB0 = *(const uint4*)(xb + rowb + XB_B + scq * 8);
        rB1 = *(const uint4*)(xb + rowb + XB_B + 64 + scq * 8);
        rC0 = *(const uint4*)(xb + rowb + XB_C + scq * 8);
        rC1 = *(const uint4*)(xb + rowb + XB_C + 64 + scq * 8);
    }
    __syncthreads();
    {
        *(uint4*)&Bl[sr * 136 + scq * 8] = rB0;
        *(uint4*)&Bl[sr * 136 + 64 + scq * 8] = rB1;
        *(uint4*)&Cl[sr * 136 + scq * 8] = rC0;
        *(uint4*)&Cl[sr * 136 + 64 + scq * 8] = rC1;
        const u16* px = (const u16*)&rXs;
        const u16* pb0 = (const u16*)&rB0;
        const u16* pb1 = (const u16*)&rB1;
        float dd = ddS[sr];
        #pragma unroll
        for (int j = 0; j < 8; ++j) {
            Xt[(scq * 8 + j) * 72 + sgrp] = px[j];
            Bt[(scq * 8 + j) * 72 + sgrp] = f2b(b2f(pb0[j]) * dd);
            Bt[(64 + scq * 8 + j) * 72 + sgrp] = f2b(b2f(pb1[j]) * dd);
        }
    }
    __syncthreads();

    for (int c = 0; c < NCHUNKx; ++c) {
        int row0 = b * LSEQ + c * CHUNKx;
        if (c + 1 < NCHUNKx) {
            size_t rowb = ((size_t)row0 + CHUNKx + sr) * LDX;
            rXs = *(const uint4*)(xb + rowb + h * 64 + scq * 8);
            rB0 = *(const uint4*)(xb + rowb + XB_B + scq * 8);
            rB1 = *(const uint4*)(xb + rowb + XB_B + 64 + scq * 8);
            rC0 = *(const uint4*)(xb + rowb + XB_C + scq * 8);
            rC1 = *(const uint4*)(xb + rowb + XB_C + 64 + scq * 8);
        }
        f32x4 accG[2], yac[2];
        accG[0] = (f32x4){0.f, 0.f, 0.f, 0.f}; accG[1] = (f32x4){0.f, 0.f, 0.f, 0.f};
        yac[0] = (f32x4){0.f, 0.f, 0.f, 0.f};  yac[1] = (f32x4){0.f, 0.f, 0.f, 0.f};
        #pragma unroll
        for (int kk = 0; kk < 4; ++kk) {
            bf16x8 aC = *(bf16x8*)&Cl[(16 * lt + l15) * 136 + 32 * kk + 8 * g];
            #pragma unroll
            for (int q = 0; q < 2; ++q) {
                int st = 16 * (2 * hf + q) + l15;
                bf16x8 bB = *(bf16x8*)&Bl[st * 136 + 32 * kk + 8 * g];
                accG[q] = __builtin_amdgcn_mfma_f32_16x16x32_bf16(aC, bB, accG[q], 0, 0, 0);
                bf16x8 bS = *(bf16x8*)&Sp[st * 136 + 32 * kk + 8 * g];
                yac[q] = __builtin_amdgcn_mfma_f32_16x16x32_bf16(aC, bS, yac[q], 0, 0, 0);
            }
        }
        float dc = dcS;
        #pragma unroll
        for (int q = 0; q < 2; ++q) {
            int s = 16 * (2 * hf + q) + l15;
            float as = acss[s], ds = dtS[s];
            #pragma unroll
            for (int j = 0; j < 4; ++j) {
                int l = 16 * lt + 4 * g + j;
                yac[q][j] *= eaS[l];
                float v = (s <= l) ? accG[q][j] * __expf(acss[l] - as) * ds : 0.f;
                Gp[l * 72 + s] = f2b(v);
            }
        }
        #pragma unroll
        for (int pt = 0; pt < 4; ++pt)
            #pragma unroll
            for (int j = 0; j < 4; ++j) sreg[pt][j] *= dc;
        __syncthreads();

        #pragma unroll
        for (int kk = 0; kk < 2; ++kk) {
            bf16x8 aG = *(bf16x8*)&Gp[(16 * lt + l15) * 72 + 32 * kk + 8 * g];
            #pragma unroll
            for (int q = 0; q < 2; ++q) {
                int row = 16 * (2 * hf + q) + l15;
                int grp = (4 * kk + g) ^ ((row >> 3) & 7);
                bf16x8 bXq = *(bf16x8*)&Xt[row * 72 + grp * 8];
                yac[q] = __builtin_amdgcn_mfma_f32_16x16x32_bf16(aG, bXq, yac[q], 0, 0, 0);
            }
            int rowb = 16 * w + l15;
            int grpb = (4 * kk + g) ^ ((rowb >> 3) & 7);
            bf16x8 aB = *(bf16x8*)&Bt[rowb * 72 + grpb * 8];
            #pragma unroll
            for (int pt = 0; pt < 4; ++pt) {
                int row = 16 * pt + l15;
                int grp = (4 * kk + g) ^ ((row >> 3) & 7);
                bf16x8 bX = *(bf16x8*)&Xt[row * 72 + grp * 8];
                sreg[pt] = __builtin_amdgcn_mfma_f32_16x16x32_bf16(aB, bX, sreg[pt], 0, 0, 0);
            }
        }
        #pragma unroll
        for (int q = 0; q < 2; ++q) {
            int p = 16 * (2 * hf + q) + l15;
            int ph = (p >> 3) & 7;
            #pragma unroll
            for (int j = 0; j < 4; ++j) {
                int l = 16 * lt + 4 * g + j;
                int col = (((l >> 3) ^ ph) << 3) + (l & 7);
                float xsv = b2f(Xt[p * 72 + col]);
                xb[(size_t)(row0 + l) * LDX + h * 64 + p] = f2b(yac[q][j] + Dh * xsv);
            }
        }
        if (tid < 64 && c + 1 < NCHUNKx) {
            float a = acb[(c + 1) * CHUNKx + tid];
            float a63 = __shfl(a, 63);
            float d = dtv[(size_t)(row0 + CHUNKx + tid) * NHEADSx + h];
            acss[tid] = a; eaS[tid] = __expf(a); dtS[tid] = d;
            ddS[tid] = d * __expf(a63 - a);
            if (tid == 0) dcS = __expf(a63);
        }
        __syncthreads();
        #pragma unroll
        for (int pt = 0; pt < 4; ++pt) {
            ushort4 pk;
            pk.x = f2b(sreg[pt][0]); pk.y = f2b(sreg[pt][1]);
            pk.z = f2b(sreg[pt][2]); pk.w = f2b(sreg[pt][3]);
            *(ushort4*)&Sp[(16 * pt + l15) * 136 + 16 * w + 4 * g] = pk;
        }
        if (c + 1 < NCHUNKx) {
            *(uint4*)&Bl[sr * 136 + scq * 8] = rB0;
            *(uint4*)&Bl[sr * 136 + 64 + scq * 8] = rB1;
            *(uint4*)&Cl[sr * 136 + scq * 8] = rC0;
            *(uint4*)&Cl[sr * 136 + 64 + scq * 8] = rC1;
            const u16* px = (const u16*)&rXs;
            const u16* pb0 = (const u16*)&rB0;
            const u16* pb1 = (const u16*)&rB1;
            float dd = ddS[sr];
            #pragma unroll
            for (int j = 0; j < 8; ++j) {
                Xt[(scq * 8 + j) * 72 + sgrp] = px[j];
                Bt[(scq * 8 + j) * 72 + sgrp] = f2b(b2f(pb0[j]) * dd);
                Bt[(64 + scq * 8 + j) * 72 + sgrp] = f2b(b2f(pb1[j]) * dd);
            }
        }
        __syncthreads();
    }
}

// ---------- gated RMSNorm in place over y ----------
__global__ __launch_bounds__(256) void rmsgate_k(u16* __restrict__ xb,
                                                 const u16* __restrict__ zb,
                                                 const float* __restrict__ w) {
    int row = blockIdx.x;
    const u16* zp = zb + (size_t)row * D_INNERx;
    u16* yp = xb + (size_t)row * LDX;
    float vals[8];
    float ss = 0.f;
    #pragma unroll
    for (int i = 0; i < 8; ++i) {
        int c = threadIdx.x + i * 256;
        float z = b2f(zp[c]);
        float y = b2f(yp[c]) * silu_f(z);
        vals[i] = y; ss += y * y;
    }
    float tot = block_sum(ss);
    float scale = rsqrtf(tot * (1.f / D_INNERx) + 1e-5f);
    #pragma unroll
    for (int i = 0; i < 8; ++i) {
        int c = threadIdx.x + i * 256;
        yp[c] = f2b(vals[i] * scale * w[c]);
    }
}

// ---------- hidden = out[:, -1, :] ----------
__global__ void hidden_k(float* __restrict__ out) {
    int i = blockIdx.x * blockDim.x + threadIdx.x;
    int b = i >> 10, d = i & 1023;
    out[(size_t)NTOK * D_MODELx + i] = out[((size_t)(b * LSEQ + LSEQ - 1)) * D_MODELx + d];
}

extern "C" void kernel_launch(void* const* d_in, const int* in_sizes, int n_in,
                              void* d_out, int out_size, void* d_ws, size_t ws_size,
                              hipStream_t stream) {
    const float* x       = (const float*)d_in[0];
    const float* Wi      = (const float*)d_in[1];
    const float* bi      = (const float*)d_in[2];
    const float* ln_g    = (const float*)d_in[3];
    const float* ln_b    = (const float*)d_in[4];
    const float* Win     = (const float*)d_in[5];
    const float* conv_w  = (const float*)d_in[6];
    const float* conv_b  = (const float*)d_in[7];
    const float* dt_bias = (const float*)d_in[8];
    const float* A_log   = (const float*)d_in[9];
    const float* Dv      = (const float*)d_in[10];
    const float* rms_w   = (const float*)d_in[11];
    const float* Wout    = (const float*)d_in[12];
    float* out = (float*)d_out;

    if (ws_size < 118489088ull) return;
    u16* xb  = (u16*)d_ws;                                   // [NTOK][LDX] bf16
    u16* ub  = xb + (size_t)NTOK * LDX;                      // [NTOK][1024] bf16
    u16* Woutb = ub;                                         // overlay after y ready
    u16* Rb  = ub + (size_t)NTOK * D_MODELx;                 // 8 MiB region
    u16* Wib  = Rb;                                          // 1024x1024
    u16* Winb = Rb + (size_t)1024 * 1024;                    // up to 2560x1024 (padded)
    float* acs = (float*)Rb;                                 // overlays Wib/Winb after GEMMs
    float* dtv = acs + (size_t)B_N * NHEADSx * NCHUNKx * CHUNKx;
    u16* xbf = xb;
    u16* zb  = (u16*)d_out;

    // 0. conversions
    cvt_f2b_k<<<16384, 256, 0, stream>>>(x, xbf, 16777216 / 4);
    cvt_f2b_k<<<1024, 256, 0, stream>>>(Wi, Wib, 1048576 / 4);
    // 1. u = x @ Wi^T + bi
    gemm_big<1><<<dim3(4, 64), 512, 0, stream>>>(
        xbf, Wib, bi, ub, NTOK, D_MODELx, D_INx, D_INx, D_MODELx);
    // 2. LayerNorm
    layernorm_k<<<NTOK, 256, 0, stream>>>(ub, ln_g, ln_b);
    // 3a. z = u @ Win[0:2048]^T -> d_out
    cvt_f2b_k<<<2048, 256, 0, stream>>>(Win, Winb, (2048 * 1024) / 4);
    gemm_big<1><<<dim3(8, 64), 512, 0, stream>>>(
        ub, Winb, nullptr, zb, NTOK, D_INNERx, D_MODELx, D_MODELx, D_INNERx);
    // 3b. xBCdt = u @ Win[2048:4384]^T -> xb  (N=2336 ragged; Winb padded to 2560 rows)
    cvt_f2b_k<<<2336, 256, 0, stream>>>(Win + (size_t)2048 * 1024, Winb, (2336 * 1024) / 4);
    gemm_big<1><<<dim3(10, 64), 512, 0, stream>>>(
        ub, Winb, nullptr, xb, NTOK, LDX, D_MODELx, D_MODELx, LDX);
    // 4. dt + per-chunk cumsum (wave-parallel scan)
    dt_acs_k<<<2048, 256, 0, stream>>>(xb, dt_bias, A_log, dtv, acs);
    // 5. conv + silu in place
    conv_k<<<dim3(CONV_DIMx / 32, B_N), 256, 0, stream>>>(xb, conv_w, conv_b);
    // 6+7. fused SSD v3
    ssd_k<<<dim3(NHEADSx, B_N), 512, 0, stream>>>(xb, dtv, acs, Dv);
    // 8. gated RMSNorm in place over y
    rmsgate_k<<<NTOK, 256, 0, stream>>>(xb, zb, rms_w);
    // 9. out = yn @ Wout^T
    cvt_f2b_k<<<2048, 256, 0, stream>>>(Wout, Woutb, (2048 * 1024) / 4);
    gemm_big<0><<<dim3(4, 64), 512, 0, stream>>>(
        xb, Woutb, nullptr, out, NTOK, D_MODELx, D_INNERx, LDX, D_MODELx);
    // 10. hidden
    hidden_k<<<(B_N * D_MODELx) / 256, 256, 0, stream>>>(out);
}